// Round 1
// 679.692 us; speedup vs baseline: 1.1728x; 1.1728x over previous
//
#include <hip/hip_runtime.h>
#include <hip/hip_fp16.h>

#define NU 50000
#define NE 100000
#define DIM 64
#define NRELS 16
#define EKG 1500000
#define EIN 1000000

#define KG_CHUNK 8192
#define KG_NBUCK ((NE + 511) >> 9)   // 196
#define B8_CHUNK 4096
#define KG_CAP 9216                  // Binomial mean 7680, sigma 87 -> +17s
#define C8_CAP 6656                  // mean 5120, sigma 71 -> +21s

// fp16 mirror cast for layer-0 inputs
__global__ void k_castH(const float* __restrict__ ent0, const float* __restrict__ usr0,
                        __half* __restrict__ entH, __half* __restrict__ usrH) {
    int i = blockIdx.x * blockDim.x + threadIdx.x;
    if (i < NE * DIM) entH[i] = __float2half(ent0[i]);
    if (i < NU * DIM) usrH[i] = __float2half(usr0[i]);
}

// qmH[i][c] = (half) sum_k ent[i][k] * WQ[k][c]  -- f32 input
__global__ __launch_bounds__(256) void k_gemm_f(const float* __restrict__ ent,
                                                const float* __restrict__ wq,
                                                __half* __restrict__ qmH, int nrows) {
    __shared__ float sW[64 * 64];
    __shared__ float sR[4][64];
    int t = threadIdx.x;
    for (int i = t; i < 4096; i += 256) sW[i] = wq[i];
    int r = t >> 6, c = t & 63;
    int row = blockIdx.x * 4 + r;
    sR[r][c] = (row < nrows) ? ent[row * 64 + c] : 0.f;
    __syncthreads();
    float acc = 0.f;
#pragma unroll
    for (int k = 0; k < 64; k++) acc += sR[r][k] * sW[k * 64 + c];
    if (row < nrows) qmH[row * 64 + c] = __float2half(acc);
}

// same, fp16 input
__global__ __launch_bounds__(256) void k_gemm_h(const __half* __restrict__ ent,
                                                const float* __restrict__ wq,
                                                __half* __restrict__ qmH, int nrows) {
    __shared__ float sW[64 * 64];
    __shared__ float sR[4][64];
    int t = threadIdx.x;
    for (int i = t; i < 4096; i += 256) sW[i] = wq[i];
    int r = t >> 6, c = t & 63;
    int row = blockIdx.x * 4 + r;
    sR[r][c] = (row < nrows) ? __half2float(ent[row * 64 + c]) : 0.f;
    __syncthreads();
    float acc = 0.f;
#pragma unroll
    for (int k = 0; k < 64; k++) acc += sR[r][k] * sW[k * 64 + c];
    if (row < nrows) qmH[row * 64 + c] = __float2half(acc);
}

// ---- bucket-level histogram (LDS-privatized; replaces 3.5M global atomics) ----
__global__ __launch_bounds__(256) void k_hist_bucket(const int* __restrict__ eh,
        const int* __restrict__ iu, const int* __restrict__ ii,
        int* __restrict__ cntK, int* __restrict__ cntU, int* __restrict__ cntI) {
    __shared__ int sK[256], sU[256], sI[256];
    int t = threadIdx.x;
    sK[t] = 0; sU[t] = 0; sI[t] = 0;
    __syncthreads();
    int stride = gridDim.x * 256;
    for (int e = blockIdx.x * 256 + t; e < EKG; e += stride)
        atomicAdd(&sK[eh[e] >> 9], 1);
    for (int e = blockIdx.x * 256 + t; e < EIN; e += stride) {
        atomicAdd(&sU[iu[e] >> 8], 1);
        atomicAdd(&sI[ii[e] >> 9], 1);
    }
    __syncthreads();
    if (sK[t]) atomicAdd(&cntK[t], sK[t]);
    if (sU[t]) atomicAdd(&cntU[t], sU[t]);
    if (sI[t]) atomicAdd(&cntI[t], sI[t]);
}

// ---- tiny 196-entry scans: bucket counts -> bucket offsets + gcur init ----
__global__ __launch_bounds__(256) void k_bucket_scan(const int* __restrict__ cntK,
        const int* __restrict__ cntU, const int* __restrict__ cntI,
        int* __restrict__ kg_boff, int* __restrict__ ui_boff, int* __restrict__ iu_boff,
        int* __restrict__ kg_g, int* __restrict__ ui_g, int* __restrict__ iu_g) {
    __shared__ int sc[256];
    int t = threadIdx.x;
#define SCAN1(cnt, boff, gcur) { \
    int v = cnt[t]; sc[t] = v; __syncthreads(); \
    for (int o = 1; o < 256; o <<= 1) { \
        int u = (t >= o) ? sc[t - o] : 0; __syncthreads(); sc[t] += u; __syncthreads(); } \
    int e = sc[t] - v; boff[t] = e; gcur[t] = e; \
    __syncthreads(); }
    SCAN1(cntK, kg_boff, kg_g)
    SCAN1(cntU, ui_boff, ui_g)
    SCAN1(cntI, iu_boff, iu_g)
#undef SCAN1
}

// ---- pass B: bin KG edges into node-range buckets (LDS staged, coalesced flush)
__global__ __launch_bounds__(256) void k_binB_kg(const int* __restrict__ eh,
        const int* __restrict__ et, const int* __restrict__ ety,
        int* __restrict__ gcur, unsigned* __restrict__ tmp) {
    __shared__ unsigned stage[KG_CHUNK];
    __shared__ int dest[KG_CHUNK];
    __shared__ int cnt[KG_NBUCK], boff[KG_NBUCK], gbase[KG_NBUCK], curl[KG_NBUCK];
    __shared__ int sc[256];
    int t = threadIdx.x;
    int base = blockIdx.x * KG_CHUNK;
    int nloc = EKG - base; if (nloc > KG_CHUNK) nloc = KG_CHUNK;
    for (int i = t; i < KG_NBUCK; i += 256) cnt[i] = 0;
    __syncthreads();
    for (int i = t; i < nloc; i += 256)
        atomicAdd(&cnt[eh[base + i] >> 9], 1);
    __syncthreads();
    int v = (t < KG_NBUCK) ? cnt[t] : 0;
    sc[t] = v;
    __syncthreads();
    for (int o = 1; o < 256; o <<= 1) {
        int u = (t >= o) ? sc[t - o] : 0;
        __syncthreads();
        sc[t] += u;
        __syncthreads();
    }
    if (t < KG_NBUCK) {
        boff[t] = sc[t] - v;
        curl[t] = sc[t] - v;
        gbase[t] = atomicAdd(&gcur[t], v);
    }
    __syncthreads();
    for (int i = t; i < nloc; i += 256) {
        int e = base + i;
        int h = eh[e];
        int b = h >> 9;
        unsigned pay = (unsigned)et[e] | ((unsigned)(ety[e] - 1) << 17)
                     | ((unsigned)(h & 511) << 21);
        int pos = atomicAdd(&curl[b], 1);
        stage[pos] = pay;
        dest[pos] = gbase[b] + (pos - boff[b]);
    }
    __syncthreads();
    for (int s = t; s < nloc; s += 256) tmp[dest[s]] = stage[s];
}

// ---- pass B generic, 8B payload {aux|low<<auxShift, w}
__global__ __launch_bounds__(256) void k_binB8(const int* __restrict__ key,
        const int* __restrict__ aux, const float* __restrict__ wv, int nE,
        int shift, int auxShift, int* __restrict__ gcur, int2* __restrict__ tmp) {
    __shared__ int2 stage[B8_CHUNK];
    __shared__ int dest[B8_CHUNK];
    __shared__ int cnt[256], boff[256], gbase[256], curl[256];
    __shared__ int sc[256];
    int t = threadIdx.x;
    int base = blockIdx.x * B8_CHUNK;
    int nloc = nE - base; if (nloc > B8_CHUNK) nloc = B8_CHUNK;
    cnt[t] = 0;
    __syncthreads();
    for (int i = t; i < nloc; i += 256)
        atomicAdd(&cnt[key[base + i] >> shift], 1);
    __syncthreads();
    int v = cnt[t];
    sc[t] = v;
    __syncthreads();
    for (int o = 1; o < 256; o <<= 1) {
        int u = (t >= o) ? sc[t - o] : 0;
        __syncthreads();
        sc[t] += u;
        __syncthreads();
    }
    boff[t] = sc[t] - v;
    curl[t] = sc[t] - v;
    gbase[t] = atomicAdd(&gcur[t], v);
    __syncthreads();
    int lowmask = (1 << shift) - 1;
    for (int i = t; i < nloc; i += 256) {
        int e = base + i;
        int k = key[e];
        int b = k >> shift;
        int2 pay;
        pay.x = aux[e] | ((k & lowmask) << auxShift);
        pay.y = __float_as_int(wv[e]);
        int pos = atomicAdd(&curl[b], 1);
        stage[pos] = pay;
        dest[pos] = gbase[b] + (pos - boff[b]);
    }
    __syncthreads();
    for (int s = t; s < nloc; s += 256) tmp[dest[s]] = stage[s];
}

// ---- pass C: within-bucket counting sort into final CSR (LDS staged).
// Now also derives per-node counts locally and WRITES the per-node CSR offsets,
// eliminating the global per-node histogram + 3-kernel scan chain.
__global__ __launch_bounds__(256) void k_binC_kg(const unsigned* __restrict__ tmp,
        const int* __restrict__ boff, unsigned* __restrict__ dst,
        int* __restrict__ off) {
    __shared__ unsigned stage[KG_CAP];
    __shared__ int curl[512];
    __shared__ int sc[256];
    int b = blockIdx.x;
    int nbase = b << 9;
    int nlim = NE - nbase; if (nlim > 512) nlim = 512;
    if (nlim <= 0) return;
    int t = threadIdx.x;
    int r0 = boff[b];
    int r1 = boff[b + 1];
    int cntb = r1 - r0;
    curl[t] = 0; curl[t + 256] = 0;
    __syncthreads();
    // count local ids within bucket
    for (int s = t; s < cntb; s += 256)
        atomicAdd(&curl[(tmp[r0 + s] >> 21) & 511], 1);
    __syncthreads();
    // scan 512 entries (2 per thread)
    int v0 = curl[2 * t], v1 = curl[2 * t + 1];
    int s2 = v0 + v1;
    sc[t] = s2;
    __syncthreads();
    for (int o = 1; o < 256; o <<= 1) {
        int u = (t >= o) ? sc[t - o] : 0;
        __syncthreads();
        sc[t] += u;
        __syncthreads();
    }
    int excl = sc[t] - s2;
    curl[2 * t] = excl;
    curl[2 * t + 1] = excl + v0;
    // write per-node CSR offsets
    if (2 * t < nlim) off[nbase + 2 * t] = r0 + excl;
    if (2 * t + 1 < nlim) off[nbase + 2 * t + 1] = r0 + excl + v0;
    if (b == KG_NBUCK - 1 && t == 0) off[nbase + nlim] = r1;   // sentinel off[NE]
    __syncthreads();
    // place
    if (cntb <= KG_CAP) {
        for (int s = t; s < cntb; s += 256) {
            unsigned pay = tmp[r0 + s];
            int l = (pay >> 21) & 511;
            int pos = atomicAdd(&curl[l], 1);
            stage[pos] = pay;
        }
        __syncthreads();
        for (int s = t; s < cntb; s += 256) dst[r0 + s] = stage[s];
    } else {
        for (int s = t; s < cntb; s += 256) {
            unsigned pay = tmp[r0 + s];
            int l = (pay >> 21) & 511;
            int pos = atomicAdd(&curl[l], 1);
            dst[r0 + pos] = pay;
        }
    }
}

__global__ __launch_bounds__(256) void k_binC8(const int2* __restrict__ tmp,
        const int* __restrict__ boff, int2* __restrict__ dst,
        int* __restrict__ off, int nnodes, int shift, int auxShift) {
    __shared__ int2 stage[C8_CAP];
    __shared__ int curl[512];
    __shared__ int sc[256];
    int b = blockIdx.x;
    int nbase = b << shift;
    int nlim = nnodes - nbase; if (nlim > (1 << shift)) nlim = 1 << shift;
    if (nlim <= 0) return;
    int t = threadIdx.x;
    int r0 = boff[b];
    int r1 = boff[b + 1];
    int cntb = r1 - r0;
    int lowmask = (1 << shift) - 1;
    curl[t] = 0; curl[t + 256] = 0;
    __syncthreads();
    for (int s = t; s < cntb; s += 256)
        atomicAdd(&curl[(tmp[r0 + s].x >> auxShift) & lowmask], 1);
    __syncthreads();
    int v0 = curl[2 * t], v1 = curl[2 * t + 1];
    int s2 = v0 + v1;
    sc[t] = s2;
    __syncthreads();
    for (int o = 1; o < 256; o <<= 1) {
        int u = (t >= o) ? sc[t - o] : 0;
        __syncthreads();
        sc[t] += u;
        __syncthreads();
    }
    int excl = sc[t] - s2;
    curl[2 * t] = excl;
    curl[2 * t + 1] = excl + v0;
    if (2 * t < nlim) off[nbase + 2 * t] = r0 + excl;
    if (2 * t + 1 < nlim) off[nbase + 2 * t + 1] = r0 + excl + v0;
    if (b == gridDim.x - 1 && t == 0) off[nbase + nlim] = r1;  // sentinel
    __syncthreads();
    if (cntb <= C8_CAP) {
        for (int s = t; s < cntb; s += 256) {
            int2 pay = tmp[r0 + s];
            int l = (pay.x >> auxShift) & lowmask;
            int pos = atomicAdd(&curl[l], 1);
            stage[pos] = pay;
        }
        __syncthreads();
        for (int s = t; s < cntb; s += 256) dst[r0 + s] = stage[s];
    } else {
        for (int s = t; s < cntb; s += 256) {
            int2 pay = tmp[r0 + s];
            int l = (pay.x >> auxShift) & lowmask;
            int pos = atomicAdd(&curl[l], 1);
            dst[r0 + pos] = pay;
        }
    }
}

#define SHFL_RED(p) \
    p += __shfl_xor(p, 16, 64); p += __shfl_xor(p, 8, 64); \
    p += __shfl_xor(p, 4, 64);  p += __shfl_xor(p, 2, 64); \
    p += __shfl_xor(p, 1, 64);

// fused per-node entity aggregation (fp16 gathers, f32 math)
__global__ __launch_bounds__(256) void k_ent(const __half* __restrict__ qmH,
        const float* __restrict__ relf, const __half* __restrict__ entH,
        const __half* __restrict__ usrH,
        const int* __restrict__ kg_off, const unsigned* __restrict__ kg_tr,
        const int* __restrict__ iu_off, const int2* __restrict__ iu_iw,
        float* __restrict__ eacc, __half* __restrict__ entHout) {
    int w = __builtin_amdgcn_readfirstlane(threadIdx.x >> 6);
    int node = blockIdx.x * 4 + w;
    if (node >= NE) return;
    int d = threadIdx.x & 63;
    const float SC = 0.17677669529663687f; // 1/sqrt(32)
    float qh = __half2float(qmH[(long)node * 64 + d]);
    int b0 = kg_off[node], b1 = kg_off[node + 1];
    int deg = b1 - b0;

    float m = -INFINITY, ssum = 0.f, acc = 0.f;
    int s = b0;
    for (; s + 4 <= b1; s += 4) {
        float sc[4], val[4];
#pragma unroll
        for (int j = 0; j < 4; j++) {
            unsigned tr = kg_tr[s + j];
            int tl = tr & 0x1FFFF, rr = (tr >> 17) & 15;
            float rl = relf[rr * 64 + d];
            float qt = __half2float(qmH[(long)tl * 64 + d]);
            val[j] = __half2float(entH[(long)tl * 64 + d]) * rl;
            float p = qh * qt * rl;
            SHFL_RED(p)
            sc[j] = p * SC;
        }
        float cmax = fmaxf(fmaxf(sc[0], sc[1]), fmaxf(sc[2], sc[3]));
        float mn = fmaxf(m, cmax);
        float scale = __expf(m - mn);
        ssum *= scale; acc *= scale;
#pragma unroll
        for (int j = 0; j < 4; j++) {
            float e = __expf(sc[j] - mn);
            ssum += e;
            acc += val[j] * e;
        }
        m = mn;
    }
    for (; s < b1; s++) {
        unsigned tr = kg_tr[s];
        int tl = tr & 0x1FFFF, rr = (tr >> 17) & 15;
        float rl = relf[rr * 64 + d];
        float qt = __half2float(qmH[(long)tl * 64 + d]);
        float v = __half2float(entH[(long)tl * 64 + d]) * rl;
        float p = qh * qt * rl;
        SHFL_RED(p)
        float scv = p * SC;
        float mn = fmaxf(m, scv);
        float scale = __expf(m - mn);
        float e = __expf(scv - mn);
        ssum = ssum * scale + e;
        acc = acc * scale + v * e;
        m = mn;
    }
    if (deg > 0) acc /= ssum;

    float ss = acc * acc;
    SHFL_RED(ss)
    ss += __shfl_xor(ss, 32, 64);
    float scale = 1.f / fmaxf(sqrtf(ss), 1e-12f);
    acc *= scale;

    int c0 = iu_off[node], c1 = iu_off[node + 1];
    int t = c0;
    for (; t + 4 <= c1; t += 4) {
        int2 p0 = iu_iw[t + 0], p1 = iu_iw[t + 1], p2 = iu_iw[t + 2], p3 = iu_iw[t + 3];
        float a0 = __int_as_float(p0.y) * __half2float(usrH[(long)(p0.x & 0xFFFF) * 64 + d]);
        float a1 = __int_as_float(p1.y) * __half2float(usrH[(long)(p1.x & 0xFFFF) * 64 + d]);
        float a2 = __int_as_float(p2.y) * __half2float(usrH[(long)(p2.x & 0xFFFF) * 64 + d]);
        float a3 = __int_as_float(p3.y) * __half2float(usrH[(long)(p3.x & 0xFFFF) * 64 + d]);
        acc += (a0 + a1) + (a2 + a3);
    }
    for (; t < c1; t++) {
        int2 pw = iu_iw[t];
        acc += __int_as_float(pw.y) * __half2float(usrH[(long)(pw.x & 0xFFFF) * 64 + d]);
    }
    long idx = (long)node * 64 + d;
    eacc[idx] += acc;
    entHout[idx] = __float2half(acc);
}

// user <- item gather (fp16 rows)
__global__ __launch_bounds__(256) void k_usr(const __half* __restrict__ entH,
        const int* __restrict__ ui_off, const int2* __restrict__ ui_iw,
        float* __restrict__ uacc, __half* __restrict__ usrHout) {
    int w = __builtin_amdgcn_readfirstlane(threadIdx.x >> 6);
    int node = blockIdx.x * 4 + w;
    if (node >= NU) return;
    int d = threadIdx.x & 63;
    int b0 = ui_off[node], b1 = ui_off[node + 1];
    float acc = 0.f;
    int s = b0;
    for (; s + 4 <= b1; s += 4) {
        int2 p0 = ui_iw[s + 0], p1 = ui_iw[s + 1], p2 = ui_iw[s + 2], p3 = ui_iw[s + 3];
        float a0 = __int_as_float(p0.y) * __half2float(entH[(long)(p0.x & 0x1FFFF) * 64 + d]);
        float a1 = __int_as_float(p1.y) * __half2float(entH[(long)(p1.x & 0x1FFFF) * 64 + d]);
        float a2 = __int_as_float(p2.y) * __half2float(entH[(long)(p2.x & 0x1FFFF) * 64 + d]);
        float a3 = __int_as_float(p3.y) * __half2float(entH[(long)(p3.x & 0x1FFFF) * 64 + d]);
        acc += (a0 + a1) + (a2 + a3);
    }
    for (; s < b1; s++) {
        int2 pw = ui_iw[s];
        acc += __int_as_float(pw.y) * __half2float(entH[(long)(pw.x & 0x1FFFF) * 64 + d]);
    }
    long idx = (long)node * 64 + d;
    uacc[idx] += acc;
    usrHout[idx] = __float2half(acc);
}

// out = concat((usr0 + uacc)/3, (ent0 + eacc)/3)
__global__ void k_final(const float* __restrict__ usr0, const float* __restrict__ uacc,
                        const float* __restrict__ ent0, const float* __restrict__ eacc,
                        float* __restrict__ out) {
    int i = blockIdx.x * blockDim.x + threadIdx.x;
    const float inv3 = 1.f / 3.f;
    if (i < NU * DIM) {
        out[i] = (usr0[i] + uacc[i]) * inv3;
    } else if (i < (NU + NE) * DIM) {
        int j = i - NU * DIM;
        out[i] = (ent0[j] + eacc[j]) * inv3;
    }
}

extern "C" void kernel_launch(void* const* d_in, const int* in_sizes, int n_in,
                              void* d_out, int out_size, void* d_ws, size_t ws_size,
                              hipStream_t stream) {
    const float* usr0  = (const float*)d_in[1];
    const float* ent0  = (const float*)d_in[2];
    const int*   inter = (const int*)d_in[3];
    const float* iwf   = (const float*)d_in[4];
    const int*   eidx  = (const int*)d_in[5];
    const int*   etype = (const int*)d_in[6];
    const float* relf  = (const float*)d_in[7];
    const float* wqf   = (const float*)d_in[8];
    float* out = (float*)d_out;

    const int* eh = eidx;
    const int* et = eidx + EKG;
    const int* iu = inter;
    const int* ii = inter + EIN;

    // ---- workspace layout (4B words) ----
    float* p = (float*)d_ws;
    float* eacc = p;  p += (long)NE * DIM;        // contiguous accs -> one memset
    float* uacc = p;  p += (long)NU * DIM;
    __half* qmH   = (__half*)p;  p += (long)NE * DIM / 2;
    __half* entHa = (__half*)p;  p += (long)NE * DIM / 2;
    __half* entHb = (__half*)p;  p += (long)NE * DIM / 2;
    __half* usrHa = (__half*)p;  p += (long)NU * DIM / 2;
    __half* usrHb = (__half*)p;  p += (long)NU * DIM / 2;
    int* cntK = (int*)p;        p += 256;         // bucket counts (contiguous -> one memset)
    int* cntU = (int*)p;        p += 256;
    int* cntI = (int*)p;        p += 256;
    int* kg_boff = (int*)p;     p += 256;         // bucket offsets (pristine)
    int* ui_boff = (int*)p;     p += 256;
    int* iu_boff = (int*)p;     p += 256;
    int* kg_off = (int*)p;      p += NE + 2;      // per-node CSR offsets (written by pass C)
    int* ui_off = (int*)p;      p += NU + 2;
    int* iu_off = (int*)p;      p += NE + 2;
    int* kg_g   = (int*)p;      p += 256;         // pass-B reservation cursors
    int* ui_g   = (int*)p;      p += 256;
    int* iu_g   = (int*)p;      p += 256;
    unsigned* kg_tr  = (unsigned*)p; p += EKG;
    unsigned* kg_tmp = (unsigned*)p; p += EKG;
    int2* ui_iw  = (int2*)p;    p += (long)EIN * 2;
    int2* ui_tmp = (int2*)p;    p += (long)EIN * 2;
    int2* iu_iw  = (int2*)p;    p += (long)EIN * 2;
    int2* iu_tmp = (int2*)p;    p += (long)EIN * 2;

    const int B = 256;

    // ---- init: zero accumulators + bucket counters; layer-0 fp16 mirrors ----
    hipMemsetAsync(eacc, 0, (size_t)(NE + NU) * DIM * 4, stream);
    hipMemsetAsync(cntK, 0, (size_t)768 * 4, stream);
    k_castH<<<(NE * DIM + B - 1) / B, B, 0, stream>>>(ent0, usr0, entHa, usrHa);

    // ---- CSR build: bucket hist -> tiny scan -> bin B -> bin C (writes per-node offsets) ----
    k_hist_bucket<<<512, 256, 0, stream>>>(eh, iu, ii, cntK, cntU, cntI);
    k_bucket_scan<<<1, 256, 0, stream>>>(cntK, cntU, cntI, kg_boff, ui_boff, iu_boff,
                                         kg_g, ui_g, iu_g);
    k_binB_kg<<<(EKG + KG_CHUNK - 1) / KG_CHUNK, 256, 0, stream>>>(eh, et, etype, kg_g, kg_tmp);
    k_binB8<<<(EIN + B8_CHUNK - 1) / B8_CHUNK, 256, 0, stream>>>(iu, ii, iwf, EIN, 8, 17, ui_g, ui_tmp);
    k_binB8<<<(EIN + B8_CHUNK - 1) / B8_CHUNK, 256, 0, stream>>>(ii, iu, iwf, EIN, 9, 16, iu_g, iu_tmp);
    k_binC_kg<<<KG_NBUCK, 256, 0, stream>>>(kg_tmp, kg_boff, kg_tr, kg_off);
    k_binC8<<<(NU + 255) >> 8, 256, 0, stream>>>(ui_tmp, ui_boff, ui_iw, ui_off, NU, 8, 17);
    k_binC8<<<(NE + 511) >> 9, 256, 0, stream>>>(iu_tmp, iu_boff, iu_iw, iu_off, NE, 9, 16);

    // ---- layer 0 ----
    k_gemm_f<<<NE / 4, 256, 0, stream>>>(ent0, wqf, qmH, NE);
    k_ent<<<(NE + 3) / 4, 256, 0, stream>>>(qmH, relf, entHa, usrHa,
                                            kg_off, kg_tr, iu_off, iu_iw, eacc, entHb);
    k_usr<<<(NU + 3) / 4, 256, 0, stream>>>(entHa, ui_off, ui_iw, uacc, usrHb);
    // ---- layer 1 ----
    k_gemm_h<<<NE / 4, 256, 0, stream>>>(entHb, wqf, qmH, NE);
    k_ent<<<(NE + 3) / 4, 256, 0, stream>>>(qmH, relf, entHb, usrHb,
                                            kg_off, kg_tr, iu_off, iu_iw, eacc, entHa);
    k_usr<<<(NU + 3) / 4, 256, 0, stream>>>(entHb, ui_off, ui_iw, uacc, usrHa);

    k_final<<<((NU + NE) * DIM + B - 1) / B, B, 0, stream>>>(usr0, uacc, ent0, eacc, out);
}

// Round 2
// 674.596 us; speedup vs baseline: 1.1817x; 1.0076x over previous
//
#include <hip/hip_runtime.h>
#include <hip/hip_fp16.h>

#define NU 50000
#define NE 100000
#define DIM 64
#define NRELS 16
#define EKG 1500000
#define EIN 1000000

#define KG_CHUNK 8192
#define KG_NBUCK ((NE + 511) >> 9)   // 196
#define B8_CHUNK 4096
#define KG_CAP 9216                  // Binomial mean 7680, sigma 87 -> +17s
#define C8_CAP 6656                  // mean 5120, sigma 71 -> +21s

typedef _Float16 f16x2 __attribute__((ext_vector_type(2)));

__device__ __forceinline__ float dot2f(__half2 a, __half2 b) {
#if __has_builtin(__builtin_amdgcn_fdot2)
    union { __half2 h; f16x2 v; } ua, ub;
    ua.h = a; ub.h = b;
    return __builtin_amdgcn_fdot2(ua.v, ub.v, 0.f, false);
#else
    return __half2float(a.x) * __half2float(b.x) + __half2float(a.y) * __half2float(b.y);
#endif
}

// sum over each 16-lane row via DPP (pure VALU, no ds_bpermute)
__device__ __forceinline__ float dpp_red16(float p) {
    int t;
    t = __builtin_amdgcn_update_dpp(0, __float_as_int(p), 0xB1, 0xF, 0xF, true);  // quad_perm xor1
    p += __int_as_float(t);
    t = __builtin_amdgcn_update_dpp(0, __float_as_int(p), 0x4E, 0xF, 0xF, true);  // quad_perm xor2
    p += __int_as_float(t);
    t = __builtin_amdgcn_update_dpp(0, __float_as_int(p), 0x141, 0xF, 0xF, true); // row_half_mirror
    p += __int_as_float(t);
    t = __builtin_amdgcn_update_dpp(0, __float_as_int(p), 0x140, 0xF, 0xF, true); // row_mirror
    p += __int_as_float(t);
    return p;
}

// fp16 mirror cast for layer-0 inputs + rel table
__global__ void k_castH(const float* __restrict__ ent0, const float* __restrict__ usr0,
                        const float* __restrict__ relf,
                        __half* __restrict__ entH, __half* __restrict__ usrH,
                        __half* __restrict__ relH) {
    int i = blockIdx.x * blockDim.x + threadIdx.x;
    if (i < NE * DIM) entH[i] = __float2half(ent0[i]);
    if (i < NU * DIM) usrH[i] = __float2half(usr0[i]);
    if (i < NRELS * DIM) relH[i] = __float2half(relf[i]);
}

// qmH[i][c] = (half) sum_k ent[i][k] * WQ[k][c]  -- f32 input
__global__ __launch_bounds__(256) void k_gemm_f(const float* __restrict__ ent,
                                                const float* __restrict__ wq,
                                                __half* __restrict__ qmH, int nrows) {
    __shared__ float sW[64 * 64];
    __shared__ float sR[4][64];
    int t = threadIdx.x;
    for (int i = t; i < 4096; i += 256) sW[i] = wq[i];
    int r = t >> 6, c = t & 63;
    int row = blockIdx.x * 4 + r;
    sR[r][c] = (row < nrows) ? ent[row * 64 + c] : 0.f;
    __syncthreads();
    float acc = 0.f;
#pragma unroll
    for (int k = 0; k < 64; k++) acc += sR[r][k] * sW[k * 64 + c];
    if (row < nrows) qmH[row * 64 + c] = __float2half(acc);
}

// same, fp16 input
__global__ __launch_bounds__(256) void k_gemm_h(const __half* __restrict__ ent,
                                                const float* __restrict__ wq,
                                                __half* __restrict__ qmH, int nrows) {
    __shared__ float sW[64 * 64];
    __shared__ float sR[4][64];
    int t = threadIdx.x;
    for (int i = t; i < 4096; i += 256) sW[i] = wq[i];
    int r = t >> 6, c = t & 63;
    int row = blockIdx.x * 4 + r;
    sR[r][c] = (row < nrows) ? __half2float(ent[row * 64 + c]) : 0.f;
    __syncthreads();
    float acc = 0.f;
#pragma unroll
    for (int k = 0; k < 64; k++) acc += sR[r][k] * sW[k * 64 + c];
    if (row < nrows) qmH[row * 64 + c] = __float2half(acc);
}

// ---- bucket-level histogram (LDS-privatized) ----
__global__ __launch_bounds__(256) void k_hist_bucket(const int* __restrict__ eh,
        const int* __restrict__ iu, const int* __restrict__ ii,
        int* __restrict__ cntK, int* __restrict__ cntU, int* __restrict__ cntI) {
    __shared__ int sK[256], sU[256], sI[256];
    int t = threadIdx.x;
    sK[t] = 0; sU[t] = 0; sI[t] = 0;
    __syncthreads();
    int stride = gridDim.x * 256;
    for (int e = blockIdx.x * 256 + t; e < EKG; e += stride)
        atomicAdd(&sK[eh[e] >> 9], 1);
    for (int e = blockIdx.x * 256 + t; e < EIN; e += stride) {
        atomicAdd(&sU[iu[e] >> 8], 1);
        atomicAdd(&sI[ii[e] >> 9], 1);
    }
    __syncthreads();
    if (sK[t]) atomicAdd(&cntK[t], sK[t]);
    if (sU[t]) atomicAdd(&cntU[t], sU[t]);
    if (sI[t]) atomicAdd(&cntI[t], sI[t]);
}

// ---- tiny scans: bucket counts -> bucket offsets + gcur init ----
__global__ __launch_bounds__(256) void k_bucket_scan(const int* __restrict__ cntK,
        const int* __restrict__ cntU, const int* __restrict__ cntI,
        int* __restrict__ kg_boff, int* __restrict__ ui_boff, int* __restrict__ iu_boff,
        int* __restrict__ kg_g, int* __restrict__ ui_g, int* __restrict__ iu_g) {
    __shared__ int sc[256];
    int t = threadIdx.x;
#define SCAN1(cnt, boff, gcur) { \
    int v = cnt[t]; sc[t] = v; __syncthreads(); \
    for (int o = 1; o < 256; o <<= 1) { \
        int u = (t >= o) ? sc[t - o] : 0; __syncthreads(); sc[t] += u; __syncthreads(); } \
    int e = sc[t] - v; boff[t] = e; gcur[t] = e; \
    __syncthreads(); }
    SCAN1(cntK, kg_boff, kg_g)
    SCAN1(cntU, ui_boff, ui_g)
    SCAN1(cntI, iu_boff, iu_g)
#undef SCAN1
}

// ---- pass B: bin KG edges into node-range buckets (LDS staged, coalesced flush)
__global__ __launch_bounds__(256) void k_binB_kg(const int* __restrict__ eh,
        const int* __restrict__ et, const int* __restrict__ ety,
        int* __restrict__ gcur, unsigned* __restrict__ tmp) {
    __shared__ unsigned stage[KG_CHUNK];
    __shared__ int dest[KG_CHUNK];
    __shared__ int cnt[KG_NBUCK], boff[KG_NBUCK], gbase[KG_NBUCK], curl[KG_NBUCK];
    __shared__ int sc[256];
    int t = threadIdx.x;
    int base = blockIdx.x * KG_CHUNK;
    int nloc = EKG - base; if (nloc > KG_CHUNK) nloc = KG_CHUNK;
    for (int i = t; i < KG_NBUCK; i += 256) cnt[i] = 0;
    __syncthreads();
    for (int i = t; i < nloc; i += 256)
        atomicAdd(&cnt[eh[base + i] >> 9], 1);
    __syncthreads();
    int v = (t < KG_NBUCK) ? cnt[t] : 0;
    sc[t] = v;
    __syncthreads();
    for (int o = 1; o < 256; o <<= 1) {
        int u = (t >= o) ? sc[t - o] : 0;
        __syncthreads();
        sc[t] += u;
        __syncthreads();
    }
    if (t < KG_NBUCK) {
        boff[t] = sc[t] - v;
        curl[t] = sc[t] - v;
        gbase[t] = atomicAdd(&gcur[t], v);
    }
    __syncthreads();
    for (int i = t; i < nloc; i += 256) {
        int e = base + i;
        int h = eh[e];
        int b = h >> 9;
        unsigned pay = (unsigned)et[e] | ((unsigned)(ety[e] - 1) << 17)
                     | ((unsigned)(h & 511) << 21);
        int pos = atomicAdd(&curl[b], 1);
        stage[pos] = pay;
        dest[pos] = gbase[b] + (pos - boff[b]);
    }
    __syncthreads();
    for (int s = t; s < nloc; s += 256) tmp[dest[s]] = stage[s];
}

// ---- pass B generic, 8B payload {aux|low<<auxShift, w}
__global__ __launch_bounds__(256) void k_binB8(const int* __restrict__ key,
        const int* __restrict__ aux, const float* __restrict__ wv, int nE,
        int shift, int auxShift, int* __restrict__ gcur, int2* __restrict__ tmp) {
    __shared__ int2 stage[B8_CHUNK];
    __shared__ int dest[B8_CHUNK];
    __shared__ int cnt[256], boff[256], gbase[256], curl[256];
    __shared__ int sc[256];
    int t = threadIdx.x;
    int base = blockIdx.x * B8_CHUNK;
    int nloc = nE - base; if (nloc > B8_CHUNK) nloc = B8_CHUNK;
    cnt[t] = 0;
    __syncthreads();
    for (int i = t; i < nloc; i += 256)
        atomicAdd(&cnt[key[base + i] >> shift], 1);
    __syncthreads();
    int v = cnt[t];
    sc[t] = v;
    __syncthreads();
    for (int o = 1; o < 256; o <<= 1) {
        int u = (t >= o) ? sc[t - o] : 0;
        __syncthreads();
        sc[t] += u;
        __syncthreads();
    }
    boff[t] = sc[t] - v;
    curl[t] = sc[t] - v;
    gbase[t] = atomicAdd(&gcur[t], v);
    __syncthreads();
    int lowmask = (1 << shift) - 1;
    for (int i = t; i < nloc; i += 256) {
        int e = base + i;
        int k = key[e];
        int b = k >> shift;
        int2 pay;
        pay.x = aux[e] | ((k & lowmask) << auxShift);
        pay.y = __float_as_int(wv[e]);
        int pos = atomicAdd(&curl[b], 1);
        stage[pos] = pay;
        dest[pos] = gbase[b] + (pos - boff[b]);
    }
    __syncthreads();
    for (int s = t; s < nloc; s += 256) tmp[dest[s]] = stage[s];
}

// ---- pass C: within-bucket counting sort into final CSR; writes per-node offsets
__global__ __launch_bounds__(256) void k_binC_kg(const unsigned* __restrict__ tmp,
        const int* __restrict__ boff, unsigned* __restrict__ dst,
        int* __restrict__ off) {
    __shared__ unsigned stage[KG_CAP];
    __shared__ int curl[512];
    __shared__ int sc[256];
    int b = blockIdx.x;
    int nbase = b << 9;
    int nlim = NE - nbase; if (nlim > 512) nlim = 512;
    if (nlim <= 0) return;
    int t = threadIdx.x;
    int r0 = boff[b];
    int r1 = boff[b + 1];
    int cntb = r1 - r0;
    curl[t] = 0; curl[t + 256] = 0;
    __syncthreads();
    for (int s = t; s < cntb; s += 256)
        atomicAdd(&curl[(tmp[r0 + s] >> 21) & 511], 1);
    __syncthreads();
    int v0 = curl[2 * t], v1 = curl[2 * t + 1];
    int s2 = v0 + v1;
    sc[t] = s2;
    __syncthreads();
    for (int o = 1; o < 256; o <<= 1) {
        int u = (t >= o) ? sc[t - o] : 0;
        __syncthreads();
        sc[t] += u;
        __syncthreads();
    }
    int excl = sc[t] - s2;
    curl[2 * t] = excl;
    curl[2 * t + 1] = excl + v0;
    if (2 * t < nlim) off[nbase + 2 * t] = r0 + excl;
    if (2 * t + 1 < nlim) off[nbase + 2 * t + 1] = r0 + excl + v0;
    if (b == KG_NBUCK - 1 && t == 0) off[nbase + nlim] = r1;   // sentinel off[NE]
    __syncthreads();
    if (cntb <= KG_CAP) {
        for (int s = t; s < cntb; s += 256) {
            unsigned pay = tmp[r0 + s];
            int l = (pay >> 21) & 511;
            int pos = atomicAdd(&curl[l], 1);
            stage[pos] = pay;
        }
        __syncthreads();
        for (int s = t; s < cntb; s += 256) dst[r0 + s] = stage[s];
    } else {
        for (int s = t; s < cntb; s += 256) {
            unsigned pay = tmp[r0 + s];
            int l = (pay >> 21) & 511;
            int pos = atomicAdd(&curl[l], 1);
            dst[r0 + pos] = pay;
        }
    }
}

__global__ __launch_bounds__(256) void k_binC8(const int2* __restrict__ tmp,
        const int* __restrict__ boff, int2* __restrict__ dst,
        int* __restrict__ off, int nnodes, int shift, int auxShift) {
    __shared__ int2 stage[C8_CAP];
    __shared__ int curl[512];
    __shared__ int sc[256];
    int b = blockIdx.x;
    int nbase = b << shift;
    int nlim = nnodes - nbase; if (nlim > (1 << shift)) nlim = 1 << shift;
    if (nlim <= 0) return;
    int t = threadIdx.x;
    int r0 = boff[b];
    int r1 = boff[b + 1];
    int cntb = r1 - r0;
    int lowmask = (1 << shift) - 1;
    curl[t] = 0; curl[t + 256] = 0;
    __syncthreads();
    for (int s = t; s < cntb; s += 256)
        atomicAdd(&curl[(tmp[r0 + s].x >> auxShift) & lowmask], 1);
    __syncthreads();
    int v0 = curl[2 * t], v1 = curl[2 * t + 1];
    int s2 = v0 + v1;
    sc[t] = s2;
    __syncthreads();
    for (int o = 1; o < 256; o <<= 1) {
        int u = (t >= o) ? sc[t - o] : 0;
        __syncthreads();
        sc[t] += u;
        __syncthreads();
    }
    int excl = sc[t] - s2;
    curl[2 * t] = excl;
    curl[2 * t + 1] = excl + v0;
    if (2 * t < nlim) off[nbase + 2 * t] = r0 + excl;
    if (2 * t + 1 < nlim) off[nbase + 2 * t + 1] = r0 + excl + v0;
    if (b == gridDim.x - 1 && t == 0) off[nbase + nlim] = r1;  // sentinel
    __syncthreads();
    if (cntb <= C8_CAP) {
        for (int s = t; s < cntb; s += 256) {
            int2 pay = tmp[r0 + s];
            int l = (pay.x >> auxShift) & lowmask;
            int pos = atomicAdd(&curl[l], 1);
            stage[pos] = pay;
        }
        __syncthreads();
        for (int s = t; s < cntb; s += 256) dst[r0 + s] = stage[s];
    } else {
        for (int s = t; s < cntb; s += 256) {
            int2 pay = tmp[r0 + s];
            int l = (pay.x >> auxShift) & lowmask;
            int pos = atomicAdd(&curl[l], 1);
            dst[r0 + pos] = pay;
        }
    }
}

// fused per-node entity aggregation: half2 lanes (32 lanes = 64 dims),
// wave processes 2 edges at once (sub = lane>>5). DPP 16-lane score reduce.
__global__ __launch_bounds__(256) void k_ent(const __half* __restrict__ qmH,
        const __half* __restrict__ relH, const __half* __restrict__ entH,
        const __half* __restrict__ usrH,
        const int* __restrict__ kg_off, const unsigned* __restrict__ kg_tr,
        const int* __restrict__ iu_off, const int2* __restrict__ iu_iw,
        float* __restrict__ eacc, __half* __restrict__ entHout) {
    int w = __builtin_amdgcn_readfirstlane(threadIdx.x >> 6);
    int node = blockIdx.x * 4 + w;
    if (node >= NE) return;
    int lane = threadIdx.x & 63;
    int sub = lane >> 5;          // which edge of the pair
    int l = lane & 31;            // half2 index: dims 2l, 2l+1 (l<16 -> head0)
    const float SC = 0.17677669529663687f; // 1/sqrt(32)
    const float NEG = -1e30f;
    const __half2* qmH2 = (const __half2*)qmH;
    const __half2* entH2 = (const __half2*)entH;
    const __half2* relH2 = (const __half2*)relH;
    const __half2* usrH2 = (const __half2*)usrH;

    __half2 qh2 = qmH2[(long)node * 32 + l];
    int b0 = kg_off[node], b1 = kg_off[node + 1];
    int deg = b1 - b0;

    float m = NEG, ssum = 0.f, accx = 0.f, accy = 0.f;
    int s = b0;
    // 4 edges per iteration (2 wave-steps of 2)
    for (; s + 4 <= b1; s += 4) {
        float sc[2]; __half2 val[2];
#pragma unroll
        for (int j = 0; j < 2; j++) {
            unsigned tr = kg_tr[s + 2 * j + sub];
            int tl = tr & 0x1FFFF, rr = (tr >> 17) & 15;
            __half2 rl2 = relH2[rr * 32 + l];
            __half2 qt2 = qmH2[(long)tl * 32 + l];
            __half2 k2 = __hmul2(qt2, rl2);
            val[j] = __hmul2(entH2[(long)tl * 32 + l], rl2);
            float p = dot2f(qh2, k2);
            p = dpp_red16(p);
            sc[j] = p * SC;
        }
        float cmax = fmaxf(sc[0], sc[1]);
        float mn = fmaxf(m, cmax);
        float scale = __expf(m - mn);
        float e0 = __expf(sc[0] - mn);
        float e1 = __expf(sc[1] - mn);
        ssum = ssum * scale + e0 + e1;
        accx = accx * scale + __half2float(val[0].x) * e0 + __half2float(val[1].x) * e1;
        accy = accy * scale + __half2float(val[0].y) * e0 + __half2float(val[1].y) * e1;
        m = mn;
    }
    // remainder: up to 3 edges, 2 per step, sub1 gated when absent
    for (; s < b1; s += 2) {
        int idx = s + sub;
        int has = idx < b1;
        unsigned tr = kg_tr[has ? idx : (b1 - 1)];
        int tl = tr & 0x1FFFF, rr = (tr >> 17) & 15;
        __half2 rl2 = relH2[rr * 32 + l];
        __half2 qt2 = qmH2[(long)tl * 32 + l];
        __half2 k2 = __hmul2(qt2, rl2);
        __half2 val = __hmul2(entH2[(long)tl * 32 + l], rl2);
        float p = dot2f(qh2, k2);
        p = dpp_red16(p);
        float scv = has ? p * SC : NEG;
        float mn = fmaxf(m, scv);
        float scale = __expf(m - mn);
        float e = has ? __expf(scv - mn) : 0.f;
        ssum = ssum * scale + e;
        accx = accx * scale + __half2float(val.x) * e;
        accy = accy * scale + __half2float(val.y) * e;
        m = mn;
    }
    // merge the two sub-chains (per-head online-softmax states)
    {
        float mo  = __shfl_xor(m, 32, 64);
        float sso = __shfl_xor(ssum, 32, 64);
        float axo = __shfl_xor(accx, 32, 64);
        float ayo = __shfl_xor(accy, 32, 64);
        float mn = fmaxf(m, mo);
        float sA = __expf(m - mn), sB = __expf(mo - mn);
        ssum = ssum * sA + sso * sB;
        accx = accx * sA + axo * sB;
        accy = accy * sA + ayo * sB;
    }
    if (deg > 0) { accx /= ssum; accy /= ssum; }

    // L2 normalize over all 64 dims (32 lanes per group)
    float ss = accx * accx + accy * accy;
    ss += __shfl_xor(ss, 1, 64);
    ss += __shfl_xor(ss, 2, 64);
    ss += __shfl_xor(ss, 4, 64);
    ss += __shfl_xor(ss, 8, 64);
    ss += __shfl_xor(ss, 16, 64);
    float nscale = 1.f / fmaxf(sqrtf(ss), 1e-12f);
    accx *= nscale; accy *= nscale;

    // user -> entity gather, 2 edges per wave
    int c0 = iu_off[node], c1 = iu_off[node + 1];
    float uax = 0.f, uay = 0.f;
    int t2 = c0;
    for (; t2 + 4 <= c1; t2 += 4) {
        int2 p0 = iu_iw[t2 + sub];
        int2 p1 = iu_iw[t2 + 2 + sub];
        __half2 u0 = usrH2[(long)(p0.x & 0xFFFF) * 32 + l];
        __half2 u1 = usrH2[(long)(p1.x & 0xFFFF) * 32 + l];
        float w0 = __int_as_float(p0.y), w1 = __int_as_float(p1.y);
        uax += w0 * __half2float(u0.x) + w1 * __half2float(u1.x);
        uay += w0 * __half2float(u0.y) + w1 * __half2float(u1.y);
    }
    for (; t2 + 2 <= c1; t2 += 2) {
        int2 pw = iu_iw[t2 + sub];
        float wv = __int_as_float(pw.y);
        __half2 u2 = usrH2[(long)(pw.x & 0xFFFF) * 32 + l];
        uax += wv * __half2float(u2.x);
        uay += wv * __half2float(u2.y);
    }
    if (t2 + sub < c1) {
        int2 pw = iu_iw[t2 + sub];
        float wv = __int_as_float(pw.y);
        __half2 u2 = usrH2[(long)(pw.x & 0xFFFF) * 32 + l];
        uax += wv * __half2float(u2.x);
        uay += wv * __half2float(u2.y);
    }
    uax += __shfl_xor(uax, 32, 64);
    uay += __shfl_xor(uay, 32, 64);
    accx += uax; accy += uay;

    if (sub == 0) {
        long idx = (long)node * 32 + l;
        float2* eacc2 = (float2*)eacc;
        float2 ev = eacc2[idx];
        ev.x += accx; ev.y += accy;
        eacc2[idx] = ev;
        ((__half2*)entHout)[idx] = __floats2half2_rn(accx, accy);
    }
}

// user <- item gather, half2 lanes, 2 edges per wave
__global__ __launch_bounds__(256) void k_usr(const __half* __restrict__ entH,
        const int* __restrict__ ui_off, const int2* __restrict__ ui_iw,
        float* __restrict__ uacc, __half* __restrict__ usrHout) {
    int w = __builtin_amdgcn_readfirstlane(threadIdx.x >> 6);
    int node = blockIdx.x * 4 + w;
    if (node >= NU) return;
    int lane = threadIdx.x & 63;
    int sub = lane >> 5, l = lane & 31;
    const __half2* entH2 = (const __half2*)entH;
    int b0 = ui_off[node], b1 = ui_off[node + 1];
    float ax = 0.f, ay = 0.f;
    int s = b0;
    for (; s + 4 <= b1; s += 4) {
        int2 p0 = ui_iw[s + sub];
        int2 p1 = ui_iw[s + 2 + sub];
        __half2 u0 = entH2[(long)(p0.x & 0x1FFFF) * 32 + l];
        __half2 u1 = entH2[(long)(p1.x & 0x1FFFF) * 32 + l];
        float w0 = __int_as_float(p0.y), w1 = __int_as_float(p1.y);
        ax += w0 * __half2float(u0.x) + w1 * __half2float(u1.x);
        ay += w0 * __half2float(u0.y) + w1 * __half2float(u1.y);
    }
    for (; s + 2 <= b1; s += 2) {
        int2 pw = ui_iw[s + sub];
        float wv = __int_as_float(pw.y);
        __half2 u2 = entH2[(long)(pw.x & 0x1FFFF) * 32 + l];
        ax += wv * __half2float(u2.x);
        ay += wv * __half2float(u2.y);
    }
    if (s + sub < b1) {
        int2 pw = ui_iw[s + sub];
        float wv = __int_as_float(pw.y);
        __half2 u2 = entH2[(long)(pw.x & 0x1FFFF) * 32 + l];
        ax += wv * __half2float(u2.x);
        ay += wv * __half2float(u2.y);
    }
    ax += __shfl_xor(ax, 32, 64);
    ay += __shfl_xor(ay, 32, 64);
    if (sub == 0) {
        long idx = (long)node * 32 + l;
        float2* uacc2 = (float2*)uacc;
        float2 uv = uacc2[idx];
        uv.x += ax; uv.y += ay;
        uacc2[idx] = uv;
        ((__half2*)usrHout)[idx] = __floats2half2_rn(ax, ay);
    }
}

// out = concat((usr0 + uacc)/3, (ent0 + eacc)/3)
__global__ void k_final(const float* __restrict__ usr0, const float* __restrict__ uacc,
                        const float* __restrict__ ent0, const float* __restrict__ eacc,
                        float* __restrict__ out) {
    int i = blockIdx.x * blockDim.x + threadIdx.x;
    const float inv3 = 1.f / 3.f;
    if (i < NU * DIM) {
        out[i] = (usr0[i] + uacc[i]) * inv3;
    } else if (i < (NU + NE) * DIM) {
        int j = i - NU * DIM;
        out[i] = (ent0[j] + eacc[j]) * inv3;
    }
}

extern "C" void kernel_launch(void* const* d_in, const int* in_sizes, int n_in,
                              void* d_out, int out_size, void* d_ws, size_t ws_size,
                              hipStream_t stream) {
    const float* usr0  = (const float*)d_in[1];
    const float* ent0  = (const float*)d_in[2];
    const int*   inter = (const int*)d_in[3];
    const float* iwf   = (const float*)d_in[4];
    const int*   eidx  = (const int*)d_in[5];
    const int*   etype = (const int*)d_in[6];
    const float* relf  = (const float*)d_in[7];
    const float* wqf   = (const float*)d_in[8];
    float* out = (float*)d_out;

    const int* eh = eidx;
    const int* et = eidx + EKG;
    const int* iu = inter;
    const int* ii = inter + EIN;

    // ---- workspace layout (4B words) ----
    float* p = (float*)d_ws;
    float* eacc = p;  p += (long)NE * DIM;        // contiguous accs -> one memset
    float* uacc = p;  p += (long)NU * DIM;
    __half* qmH   = (__half*)p;  p += (long)NE * DIM / 2;
    __half* entHa = (__half*)p;  p += (long)NE * DIM / 2;
    __half* entHb = (__half*)p;  p += (long)NE * DIM / 2;
    __half* usrHa = (__half*)p;  p += (long)NU * DIM / 2;
    __half* usrHb = (__half*)p;  p += (long)NU * DIM / 2;
    __half* relH  = (__half*)p;  p += (long)NRELS * DIM / 2;
    int* cntK = (int*)p;        p += 256;         // bucket counts (contiguous -> one memset)
    int* cntU = (int*)p;        p += 256;
    int* cntI = (int*)p;        p += 256;
    int* kg_boff = (int*)p;     p += 256;         // bucket offsets (pristine)
    int* ui_boff = (int*)p;     p += 256;
    int* iu_boff = (int*)p;     p += 256;
    int* kg_off = (int*)p;      p += NE + 2;      // per-node CSR offsets (written by pass C)
    int* ui_off = (int*)p;      p += NU + 2;
    int* iu_off = (int*)p;      p += NE + 2;
    int* kg_g   = (int*)p;      p += 256;         // pass-B reservation cursors
    int* ui_g   = (int*)p;      p += 256;
    int* iu_g   = (int*)p;      p += 256;
    unsigned* kg_tr  = (unsigned*)p; p += EKG;
    unsigned* kg_tmp = (unsigned*)p; p += EKG;
    int2* ui_iw  = (int2*)p;    p += (long)EIN * 2;
    int2* ui_tmp = (int2*)p;    p += (long)EIN * 2;
    int2* iu_iw  = (int2*)p;    p += (long)EIN * 2;
    int2* iu_tmp = (int2*)p;    p += (long)EIN * 2;

    const int B = 256;

    // ---- init: zero accumulators + bucket counters; fp16 mirrors ----
    hipMemsetAsync(eacc, 0, (size_t)(NE + NU) * DIM * 4, stream);
    hipMemsetAsync(cntK, 0, (size_t)768 * 4, stream);
    k_castH<<<(NE * DIM + B - 1) / B, B, 0, stream>>>(ent0, usr0, relf, entHa, usrHa, relH);

    // ---- CSR build ----
    k_hist_bucket<<<512, 256, 0, stream>>>(eh, iu, ii, cntK, cntU, cntI);
    k_bucket_scan<<<1, 256, 0, stream>>>(cntK, cntU, cntI, kg_boff, ui_boff, iu_boff,
                                         kg_g, ui_g, iu_g);
    k_binB_kg<<<(EKG + KG_CHUNK - 1) / KG_CHUNK, 256, 0, stream>>>(eh, et, etype, kg_g, kg_tmp);
    k_binB8<<<(EIN + B8_CHUNK - 1) / B8_CHUNK, 256, 0, stream>>>(iu, ii, iwf, EIN, 8, 17, ui_g, ui_tmp);
    k_binB8<<<(EIN + B8_CHUNK - 1) / B8_CHUNK, 256, 0, stream>>>(ii, iu, iwf, EIN, 9, 16, iu_g, iu_tmp);
    k_binC_kg<<<KG_NBUCK, 256, 0, stream>>>(kg_tmp, kg_boff, kg_tr, kg_off);
    k_binC8<<<(NU + 255) >> 8, 256, 0, stream>>>(ui_tmp, ui_boff, ui_iw, ui_off, NU, 8, 17);
    k_binC8<<<(NE + 511) >> 9, 256, 0, stream>>>(iu_tmp, iu_boff, iu_iw, iu_off, NE, 9, 16);

    // ---- layer 0 ----
    k_gemm_f<<<NE / 4, 256, 0, stream>>>(ent0, wqf, qmH, NE);
    k_ent<<<(NE + 3) / 4, 256, 0, stream>>>(qmH, relH, entHa, usrHa,
                                            kg_off, kg_tr, iu_off, iu_iw, eacc, entHb);
    k_usr<<<(NU + 3) / 4, 256, 0, stream>>>(entHa, ui_off, ui_iw, uacc, usrHb);
    // ---- layer 1 ----
    k_gemm_h<<<NE / 4, 256, 0, stream>>>(entHb, wqf, qmH, NE);
    k_ent<<<(NE + 3) / 4, 256, 0, stream>>>(qmH, relH, entHb, usrHb,
                                            kg_off, kg_tr, iu_off, iu_iw, eacc, entHa);
    k_usr<<<(NU + 3) / 4, 256, 0, stream>>>(entHb, ui_off, ui_iw, uacc, usrHa);

    k_final<<<((NU + NE) * DIM + B - 1) / B, B, 0, stream>>>(usr0, uacc, ent0, eacc, out);
}

// Round 3
// 619.618 us; speedup vs baseline: 1.2865x; 1.0887x over previous
//
#include <hip/hip_runtime.h>
#include <hip/hip_fp16.h>

#define NU 50000
#define NE 100000
#define DIM 64
#define NRELS 16
#define EKG 1500000
#define EIN 1000000

#define KG_CHUNK 8192
#define KG_NBUCK ((NE + 511) >> 9)   // 196
#define B8_CHUNK 4096
#define KG_CAP 9216                  // Binomial mean 7680, sigma 87 -> +17s
#define C8_CAP 6656                  // mean 5120, sigma 71 -> +21s

typedef _Float16 f16x2 __attribute__((ext_vector_type(2)));

union U16 { int4 v; __half2 h[4]; };

__device__ __forceinline__ float fdot2a(__half2 a, __half2 b, float c) {
#if __has_builtin(__builtin_amdgcn_fdot2)
    union { __half2 h; f16x2 v; } ua, ub;
    ua.h = a; ub.h = b;
    return __builtin_amdgcn_fdot2(ua.v, ub.v, c, false);
#else
    return c + __half2float(a.x) * __half2float(b.x) + __half2float(a.y) * __half2float(b.y);
#endif
}

// sum over each 4-lane quad via DPP (score reduce for 8-lane edge groups: head = quad)
__device__ __forceinline__ float dpp_red4(float p) {
    int t;
    t = __builtin_amdgcn_update_dpp(0, __float_as_int(p), 0xB1, 0xF, 0xF, true);  // quad_perm xor1
    p += __int_as_float(t);
    t = __builtin_amdgcn_update_dpp(0, __float_as_int(p), 0x4E, 0xF, 0xF, true);  // quad_perm xor2
    p += __int_as_float(t);
    return p;
}

// fp16 mirror cast for layer-0 inputs + rel table
__global__ void k_castH(const float* __restrict__ ent0, const float* __restrict__ usr0,
                        const float* __restrict__ relf,
                        __half* __restrict__ entH, __half* __restrict__ usrH,
                        __half* __restrict__ relH) {
    int i = blockIdx.x * blockDim.x + threadIdx.x;
    if (i < NE * DIM) entH[i] = __float2half(ent0[i]);
    if (i < NU * DIM) usrH[i] = __float2half(usr0[i]);
    if (i < NRELS * DIM) relH[i] = __float2half(relf[i]);
}

// qmH[i][c] = (half) sum_k ent[i][k] * WQ[k][c]  -- f32 input
__global__ __launch_bounds__(256) void k_gemm_f(const float* __restrict__ ent,
                                                const float* __restrict__ wq,
                                                __half* __restrict__ qmH, int nrows) {
    __shared__ float sW[64 * 64];
    __shared__ float sR[4][64];
    int t = threadIdx.x;
    for (int i = t; i < 4096; i += 256) sW[i] = wq[i];
    int r = t >> 6, c = t & 63;
    int row = blockIdx.x * 4 + r;
    sR[r][c] = (row < nrows) ? ent[row * 64 + c] : 0.f;
    __syncthreads();
    float acc = 0.f;
#pragma unroll
    for (int k = 0; k < 64; k++) acc += sR[r][k] * sW[k * 64 + c];
    if (row < nrows) qmH[row * 64 + c] = __float2half(acc);
}

// same, fp16 input
__global__ __launch_bounds__(256) void k_gemm_h(const __half* __restrict__ ent,
                                                const float* __restrict__ wq,
                                                __half* __restrict__ qmH, int nrows) {
    __shared__ float sW[64 * 64];
    __shared__ float sR[4][64];
    int t = threadIdx.x;
    for (int i = t; i < 4096; i += 256) sW[i] = wq[i];
    int r = t >> 6, c = t & 63;
    int row = blockIdx.x * 4 + r;
    sR[r][c] = (row < nrows) ? __half2float(ent[row * 64 + c]) : 0.f;
    __syncthreads();
    float acc = 0.f;
#pragma unroll
    for (int k = 0; k < 64; k++) acc += sR[r][k] * sW[k * 64 + c];
    if (row < nrows) qmH[row * 64 + c] = __float2half(acc);
}

// ---- bucket-level histogram (LDS-privatized) ----
__global__ __launch_bounds__(256) void k_hist_bucket(const int* __restrict__ eh,
        const int* __restrict__ iu, const int* __restrict__ ii,
        int* __restrict__ cntK, int* __restrict__ cntU, int* __restrict__ cntI) {
    __shared__ int sK[256], sU[256], sI[256];
    int t = threadIdx.x;
    sK[t] = 0; sU[t] = 0; sI[t] = 0;
    __syncthreads();
    int stride = gridDim.x * 256;
    for (int e = blockIdx.x * 256 + t; e < EKG; e += stride)
        atomicAdd(&sK[eh[e] >> 9], 1);
    for (int e = blockIdx.x * 256 + t; e < EIN; e += stride) {
        atomicAdd(&sU[iu[e] >> 8], 1);
        atomicAdd(&sI[ii[e] >> 9], 1);
    }
    __syncthreads();
    if (sK[t]) atomicAdd(&cntK[t], sK[t]);
    if (sU[t]) atomicAdd(&cntU[t], sU[t]);
    if (sI[t]) atomicAdd(&cntI[t], sI[t]);
}

// ---- tiny scans: bucket counts -> bucket offsets + gcur init ----
__global__ __launch_bounds__(256) void k_bucket_scan(const int* __restrict__ cntK,
        const int* __restrict__ cntU, const int* __restrict__ cntI,
        int* __restrict__ kg_boff, int* __restrict__ ui_boff, int* __restrict__ iu_boff,
        int* __restrict__ kg_g, int* __restrict__ ui_g, int* __restrict__ iu_g) {
    __shared__ int sc[256];
    int t = threadIdx.x;
#define SCAN1(cnt, boff, gcur) { \
    int v = cnt[t]; sc[t] = v; __syncthreads(); \
    for (int o = 1; o < 256; o <<= 1) { \
        int u = (t >= o) ? sc[t - o] : 0; __syncthreads(); sc[t] += u; __syncthreads(); } \
    int e = sc[t] - v; boff[t] = e; gcur[t] = e; \
    __syncthreads(); }
    SCAN1(cntK, kg_boff, kg_g)
    SCAN1(cntU, ui_boff, ui_g)
    SCAN1(cntI, iu_boff, iu_g)
#undef SCAN1
}

// ---- pass B: bin KG edges into node-range buckets (LDS staged, coalesced flush)
__global__ __launch_bounds__(256) void k_binB_kg(const int* __restrict__ eh,
        const int* __restrict__ et, const int* __restrict__ ety,
        int* __restrict__ gcur, unsigned* __restrict__ tmp) {
    __shared__ unsigned stage[KG_CHUNK];
    __shared__ int dest[KG_CHUNK];
    __shared__ int cnt[KG_NBUCK], boff[KG_NBUCK], gbase[KG_NBUCK], curl[KG_NBUCK];
    __shared__ int sc[256];
    int t = threadIdx.x;
    int base = blockIdx.x * KG_CHUNK;
    int nloc = EKG - base; if (nloc > KG_CHUNK) nloc = KG_CHUNK;
    for (int i = t; i < KG_NBUCK; i += 256) cnt[i] = 0;
    __syncthreads();
    for (int i = t; i < nloc; i += 256)
        atomicAdd(&cnt[eh[base + i] >> 9], 1);
    __syncthreads();
    int v = (t < KG_NBUCK) ? cnt[t] : 0;
    sc[t] = v;
    __syncthreads();
    for (int o = 1; o < 256; o <<= 1) {
        int u = (t >= o) ? sc[t - o] : 0;
        __syncthreads();
        sc[t] += u;
        __syncthreads();
    }
    if (t < KG_NBUCK) {
        boff[t] = sc[t] - v;
        curl[t] = sc[t] - v;
        gbase[t] = atomicAdd(&gcur[t], v);
    }
    __syncthreads();
    for (int i = t; i < nloc; i += 256) {
        int e = base + i;
        int h = eh[e];
        int b = h >> 9;
        unsigned pay = (unsigned)et[e] | ((unsigned)(ety[e] - 1) << 17)
                     | ((unsigned)(h & 511) << 21);
        int pos = atomicAdd(&curl[b], 1);
        stage[pos] = pay;
        dest[pos] = gbase[b] + (pos - boff[b]);
    }
    __syncthreads();
    for (int s = t; s < nloc; s += 256) tmp[dest[s]] = stage[s];
}

// ---- pass B generic, 8B payload {aux|low<<auxShift, w}
__global__ __launch_bounds__(256) void k_binB8(const int* __restrict__ key,
        const int* __restrict__ aux, const float* __restrict__ wv, int nE,
        int shift, int auxShift, int* __restrict__ gcur, int2* __restrict__ tmp) {
    __shared__ int2 stage[B8_CHUNK];
    __shared__ int dest[B8_CHUNK];
    __shared__ int cnt[256], boff[256], gbase[256], curl[256];
    __shared__ int sc[256];
    int t = threadIdx.x;
    int base = blockIdx.x * B8_CHUNK;
    int nloc = nE - base; if (nloc > B8_CHUNK) nloc = B8_CHUNK;
    cnt[t] = 0;
    __syncthreads();
    for (int i = t; i < nloc; i += 256)
        atomicAdd(&cnt[key[base + i] >> shift], 1);
    __syncthreads();
    int v = cnt[t];
    sc[t] = v;
    __syncthreads();
    for (int o = 1; o < 256; o <<= 1) {
        int u = (t >= o) ? sc[t - o] : 0;
        __syncthreads();
        sc[t] += u;
        __syncthreads();
    }
    boff[t] = sc[t] - v;
    curl[t] = sc[t] - v;
    gbase[t] = atomicAdd(&gcur[t], v);
    __syncthreads();
    int lowmask = (1 << shift) - 1;
    for (int i = t; i < nloc; i += 256) {
        int e = base + i;
        int k = key[e];
        int b = k >> shift;
        int2 pay;
        pay.x = aux[e] | ((k & lowmask) << auxShift);
        pay.y = __float_as_int(wv[e]);
        int pos = atomicAdd(&curl[b], 1);
        stage[pos] = pay;
        dest[pos] = gbase[b] + (pos - boff[b]);
    }
    __syncthreads();
    for (int s = t; s < nloc; s += 256) tmp[dest[s]] = stage[s];
}

// ---- pass C: within-bucket counting sort into final CSR; writes per-node offsets
__global__ __launch_bounds__(256) void k_binC_kg(const unsigned* __restrict__ tmp,
        const int* __restrict__ boff, unsigned* __restrict__ dst,
        int* __restrict__ off) {
    __shared__ unsigned stage[KG_CAP];
    __shared__ int curl[512];
    __shared__ int sc[256];
    int b = blockIdx.x;
    int nbase = b << 9;
    int nlim = NE - nbase; if (nlim > 512) nlim = 512;
    if (nlim <= 0) return;
    int t = threadIdx.x;
    int r0 = boff[b];
    int r1 = boff[b + 1];
    int cntb = r1 - r0;
    curl[t] = 0; curl[t + 256] = 0;
    __syncthreads();
    for (int s = t; s < cntb; s += 256)
        atomicAdd(&curl[(tmp[r0 + s] >> 21) & 511], 1);
    __syncthreads();
    int v0 = curl[2 * t], v1 = curl[2 * t + 1];
    int s2 = v0 + v1;
    sc[t] = s2;
    __syncthreads();
    for (int o = 1; o < 256; o <<= 1) {
        int u = (t >= o) ? sc[t - o] : 0;
        __syncthreads();
        sc[t] += u;
        __syncthreads();
    }
    int excl = sc[t] - s2;
    curl[2 * t] = excl;
    curl[2 * t + 1] = excl + v0;
    if (2 * t < nlim) off[nbase + 2 * t] = r0 + excl;
    if (2 * t + 1 < nlim) off[nbase + 2 * t + 1] = r0 + excl + v0;
    if (b == KG_NBUCK - 1 && t == 0) off[nbase + nlim] = r1;   // sentinel off[NE]
    __syncthreads();
    if (cntb <= KG_CAP) {
        for (int s = t; s < cntb; s += 256) {
            unsigned pay = tmp[r0 + s];
            int l = (pay >> 21) & 511;
            int pos = atomicAdd(&curl[l], 1);
            stage[pos] = pay;
        }
        __syncthreads();
        for (int s = t; s < cntb; s += 256) dst[r0 + s] = stage[s];
    } else {
        for (int s = t; s < cntb; s += 256) {
            unsigned pay = tmp[r0 + s];
            int l = (pay >> 21) & 511;
            int pos = atomicAdd(&curl[l], 1);
            dst[r0 + pos] = pay;
        }
    }
}

__global__ __launch_bounds__(256) void k_binC8(const int2* __restrict__ tmp,
        const int* __restrict__ boff, int2* __restrict__ dst,
        int* __restrict__ off, int nnodes, int shift, int auxShift) {
    __shared__ int2 stage[C8_CAP];
    __shared__ int curl[512];
    __shared__ int sc[256];
    int b = blockIdx.x;
    int nbase = b << shift;
    int nlim = nnodes - nbase; if (nlim > (1 << shift)) nlim = 1 << shift;
    if (nlim <= 0) return;
    int t = threadIdx.x;
    int r0 = boff[b];
    int r1 = boff[b + 1];
    int cntb = r1 - r0;
    int lowmask = (1 << shift) - 1;
    curl[t] = 0; curl[t + 256] = 0;
    __syncthreads();
    for (int s = t; s < cntb; s += 256)
        atomicAdd(&curl[(tmp[r0 + s].x >> auxShift) & lowmask], 1);
    __syncthreads();
    int v0 = curl[2 * t], v1 = curl[2 * t + 1];
    int s2 = v0 + v1;
    sc[t] = s2;
    __syncthreads();
    for (int o = 1; o < 256; o <<= 1) {
        int u = (t >= o) ? sc[t - o] : 0;
        __syncthreads();
        sc[t] += u;
        __syncthreads();
    }
    int excl = sc[t] - s2;
    curl[2 * t] = excl;
    curl[2 * t + 1] = excl + v0;
    if (2 * t < nlim) off[nbase + 2 * t] = r0 + excl;
    if (2 * t + 1 < nlim) off[nbase + 2 * t + 1] = r0 + excl + v0;
    if (b == gridDim.x - 1 && t == 0) off[nbase + nlim] = r1;  // sentinel
    __syncthreads();
    if (cntb <= C8_CAP) {
        for (int s = t; s < cntb; s += 256) {
            int2 pay = tmp[r0 + s];
            int l = (pay.x >> auxShift) & lowmask;
            int pos = atomicAdd(&curl[l], 1);
            stage[pos] = pay;
        }
        __syncthreads();
        for (int s = t; s < cntb; s += 256) dst[r0 + s] = stage[s];
    } else {
        for (int s = t; s < cntb; s += 256) {
            int2 pay = tmp[r0 + s];
            int l = (pay.x >> auxShift) & lowmask;
            int pos = atomicAdd(&curl[l], 1);
            dst[r0 + pos] = pay;
        }
    }
}

// fused per-node entity aggregation.
// 8 lanes per edge (lane holds 8 dims via one 16B load), 8 edges per wave-step:
// 24 row-gathers in flight per step. Scores are bounded (|s| << 10), so exp()
// is computed directly with NO online-max tracking (overflow-safe in f32);
// the 8 per-sub partial (ssum, acc[8]) chains merge with a plain shuffle tree.
__global__ __launch_bounds__(256) void k_ent(const __half* __restrict__ qmH,
        const __half* __restrict__ relH, const __half* __restrict__ entH,
        const __half* __restrict__ usrH,
        const int* __restrict__ kg_off, const unsigned* __restrict__ kg_tr,
        const int* __restrict__ iu_off, const int2* __restrict__ iu_iw,
        float* __restrict__ eacc, __half* __restrict__ entHout) {
    int w = __builtin_amdgcn_readfirstlane(threadIdx.x >> 6);
    int node = blockIdx.x * 4 + w;
    if (node >= NE) return;
    int lane = threadIdx.x & 63;
    int sub = lane >> 3;          // edge slot 0..7
    int li  = lane & 7;           // dims 8li..8li+7 (li<4 -> head0, li>=4 -> head1)
    const float SC = 0.17677669529663687f; // 1/sqrt(32)
    const float NEG = -1e30f;
    const int4* qmI  = (const int4*)qmH;   // row = 8 int4
    const int4* entI = (const int4*)entH;
    const int4* relI = (const int4*)relH;
    const int4* usrI = (const int4*)usrH;

    U16 qh; qh.v = qmI[(long)node * 8 + li];
    int b0 = kg_off[node], b1 = kg_off[node + 1];
    int deg = b1 - b0;

    float ssum = 0.f;
    float acc[8] = {0.f, 0.f, 0.f, 0.f, 0.f, 0.f, 0.f, 0.f};
    if (deg > 0) {
        int s = b0;
        int i0 = s + sub;
        unsigned tr = kg_tr[i0 < b1 ? i0 : b1 - 1];
        for (; s < b1; s += 8) {
            int ni = s + 8 + sub;
            unsigned trn = kg_tr[ni < b1 ? ni : b1 - 1];  // prefetch next step's payload
            bool has = (s + sub) < b1;
            int tl = tr & 0x1FFFF, rr = (tr >> 17) & 15;
            U16 rl; rl.v = relI[rr * 8 + li];
            U16 qt; qt.v = qmI[(long)tl * 8 + li];
            U16 ev; ev.v = entI[(long)tl * 8 + li];
            float p = 0.f;
#pragma unroll
            for (int k = 0; k < 4; k++) {
                __half2 kk = __hmul2(qt.h[k], rl.h[k]);
                p = fdot2a(qh.h[k], kk, p);
            }
            p = dpp_red4(p);              // per-quad sum = this lane's head score
            float e = __expf(has ? p * SC : NEG);   // exp(NEG) underflows to 0
            ssum += e;
#pragma unroll
            for (int k = 0; k < 4; k++) {
                __half2 v2 = __hmul2(ev.h[k], rl.h[k]);
                float2 vf = __half22float2(v2);
                acc[2 * k]     += vf.x * e;
                acc[2 * k + 1] += vf.y * e;
            }
            tr = trn;
        }
        // merge 8 sub-chains (plain sums; no max tracking needed)
#pragma unroll
        for (int o = 8; o <= 32; o <<= 1) {
            ssum += __shfl_xor(ssum, o, 64);
#pragma unroll
            for (int k = 0; k < 8; k++) acc[k] += __shfl_xor(acc[k], o, 64);
        }
        float inv = 1.f / ssum;
#pragma unroll
        for (int k = 0; k < 8; k++) acc[k] *= inv;
        // L2 normalize over all 64 dims
        float ss = 0.f;
#pragma unroll
        for (int k = 0; k < 8; k++) ss += acc[k] * acc[k];
        ss += __shfl_xor(ss, 1, 64);
        ss += __shfl_xor(ss, 2, 64);
        ss += __shfl_xor(ss, 4, 64);
        float nsc = 1.f / fmaxf(sqrtf(ss), 1e-12f);
#pragma unroll
        for (int k = 0; k < 8; k++) acc[k] *= nsc;
    }

    // user -> entity gather, 8 edges per step
    int c0 = iu_off[node], c1 = iu_off[node + 1];
    if (c1 > c0) {
        float ua[8] = {0.f, 0.f, 0.f, 0.f, 0.f, 0.f, 0.f, 0.f};
        int t2 = c0;
        int j0 = t2 + sub;
        int2 pw = iu_iw[j0 < c1 ? j0 : c1 - 1];
        for (; t2 < c1; t2 += 8) {
            int nj = t2 + 8 + sub;
            int2 pwn = iu_iw[nj < c1 ? nj : c1 - 1];
            bool has = (t2 + sub) < c1;
            float wv = has ? __int_as_float(pw.y) : 0.f;
            U16 uu; uu.v = usrI[(long)(pw.x & 0xFFFF) * 8 + li];
#pragma unroll
            for (int k = 0; k < 4; k++) {
                float2 uf = __half22float2(uu.h[k]);
                ua[2 * k]     += wv * uf.x;
                ua[2 * k + 1] += wv * uf.y;
            }
            pw = pwn;
        }
#pragma unroll
        for (int o = 8; o <= 32; o <<= 1) {
#pragma unroll
            for (int k = 0; k < 8; k++) ua[k] += __shfl_xor(ua[k], o, 64);
        }
#pragma unroll
        for (int k = 0; k < 8; k++) acc[k] += ua[k];
    }

    if (sub == 0) {
        long base = (long)node * 16 + 2 * li;
        float4* eacc4 = (float4*)eacc;
        float4 e0 = eacc4[base], e1 = eacc4[base + 1];
        e0.x += acc[0]; e0.y += acc[1]; e0.z += acc[2]; e0.w += acc[3];
        e1.x += acc[4]; e1.y += acc[5]; e1.z += acc[6]; e1.w += acc[7];
        eacc4[base] = e0; eacc4[base + 1] = e1;
        U16 ho;
        ho.h[0] = __floats2half2_rn(acc[0], acc[1]);
        ho.h[1] = __floats2half2_rn(acc[2], acc[3]);
        ho.h[2] = __floats2half2_rn(acc[4], acc[5]);
        ho.h[3] = __floats2half2_rn(acc[6], acc[7]);
        ((int4*)entHout)[(long)node * 8 + li] = ho.v;
    }
}

// user <- item gather, 8 lanes/edge, 8 edges per wave-step
__global__ __launch_bounds__(256) void k_usr(const __half* __restrict__ entH,
        const int* __restrict__ ui_off, const int2* __restrict__ ui_iw,
        float* __restrict__ uacc, __half* __restrict__ usrHout) {
    int w = __builtin_amdgcn_readfirstlane(threadIdx.x >> 6);
    int node = blockIdx.x * 4 + w;
    if (node >= NU) return;
    int lane = threadIdx.x & 63;
    int sub = lane >> 3, li = lane & 7;
    const int4* entI = (const int4*)entH;
    int b0 = ui_off[node], b1 = ui_off[node + 1];
    float ax[8] = {0.f, 0.f, 0.f, 0.f, 0.f, 0.f, 0.f, 0.f};
    if (b1 > b0) {
        int s = b0;
        int j0 = s + sub;
        int2 pw = ui_iw[j0 < b1 ? j0 : b1 - 1];
        for (; s < b1; s += 8) {
            int nj = s + 8 + sub;
            int2 pwn = ui_iw[nj < b1 ? nj : b1 - 1];
            bool has = (s + sub) < b1;
            float wv = has ? __int_as_float(pw.y) : 0.f;
            U16 uu; uu.v = entI[(long)(pw.x & 0x1FFFF) * 8 + li];
#pragma unroll
            for (int k = 0; k < 4; k++) {
                float2 uf = __half22float2(uu.h[k]);
                ax[2 * k]     += wv * uf.x;
                ax[2 * k + 1] += wv * uf.y;
            }
            pw = pwn;
        }
#pragma unroll
        for (int o = 8; o <= 32; o <<= 1) {
#pragma unroll
            for (int k = 0; k < 8; k++) ax[k] += __shfl_xor(ax[k], o, 64);
        }
    }
    if (sub == 0) {
        long base = (long)node * 16 + 2 * li;
        float4* uacc4 = (float4*)uacc;
        float4 u0 = uacc4[base], u1 = uacc4[base + 1];
        u0.x += ax[0]; u0.y += ax[1]; u0.z += ax[2]; u0.w += ax[3];
        u1.x += ax[4]; u1.y += ax[5]; u1.z += ax[6]; u1.w += ax[7];
        uacc4[base] = u0; uacc4[base + 1] = u1;
        U16 ho;
        ho.h[0] = __floats2half2_rn(ax[0], ax[1]);
        ho.h[1] = __floats2half2_rn(ax[2], ax[3]);
        ho.h[2] = __floats2half2_rn(ax[4], ax[5]);
        ho.h[3] = __floats2half2_rn(ax[6], ax[7]);
        ((int4*)usrHout)[(long)node * 8 + li] = ho.v;
    }
}

// out = concat((usr0 + uacc)/3, (ent0 + eacc)/3)
__global__ void k_final(const float* __restrict__ usr0, const float* __restrict__ uacc,
                        const float* __restrict__ ent0, const float* __restrict__ eacc,
                        float* __restrict__ out) {
    int i = blockIdx.x * blockDim.x + threadIdx.x;
    const float inv3 = 1.f / 3.f;
    if (i < NU * DIM) {
        out[i] = (usr0[i] + uacc[i]) * inv3;
    } else if (i < (NU + NE) * DIM) {
        int j = i - NU * DIM;
        out[i] = (ent0[j] + eacc[j]) * inv3;
    }
}

extern "C" void kernel_launch(void* const* d_in, const int* in_sizes, int n_in,
                              void* d_out, int out_size, void* d_ws, size_t ws_size,
                              hipStream_t stream) {
    const float* usr0  = (const float*)d_in[1];
    const float* ent0  = (const float*)d_in[2];
    const int*   inter = (const int*)d_in[3];
    const float* iwf   = (const float*)d_in[4];
    const int*   eidx  = (const int*)d_in[5];
    const int*   etype = (const int*)d_in[6];
    const float* relf  = (const float*)d_in[7];
    const float* wqf   = (const float*)d_in[8];
    float* out = (float*)d_out;

    const int* eh = eidx;
    const int* et = eidx + EKG;
    const int* iu = inter;
    const int* ii = inter + EIN;

    // ---- workspace layout (4B words) ----
    float* p = (float*)d_ws;
    float* eacc = p;  p += (long)NE * DIM;        // contiguous accs -> one memset
    float* uacc = p;  p += (long)NU * DIM;
    __half* qmH   = (__half*)p;  p += (long)NE * DIM / 2;
    __half* entHa = (__half*)p;  p += (long)NE * DIM / 2;
    __half* entHb = (__half*)p;  p += (long)NE * DIM / 2;
    __half* usrHa = (__half*)p;  p += (long)NU * DIM / 2;
    __half* usrHb = (__half*)p;  p += (long)NU * DIM / 2;
    __half* relH  = (__half*)p;  p += (long)NRELS * DIM / 2;
    int* cntK = (int*)p;        p += 256;         // bucket counts (contiguous -> one memset)
    int* cntU = (int*)p;        p += 256;
    int* cntI = (int*)p;        p += 256;
    int* kg_boff = (int*)p;     p += 256;         // bucket offsets (pristine)
    int* ui_boff = (int*)p;     p += 256;
    int* iu_boff = (int*)p;     p += 256;
    int* kg_off = (int*)p;      p += NE + 2;      // per-node CSR offsets (written by pass C)
    int* ui_off = (int*)p;      p += NU + 2;
    int* iu_off = (int*)p;      p += NE + 2;
    int* kg_g   = (int*)p;      p += 256;         // pass-B reservation cursors
    int* ui_g   = (int*)p;      p += 256;
    int* iu_g   = (int*)p;      p += 256;
    unsigned* kg_tr  = (unsigned*)p; p += EKG;
    unsigned* kg_tmp = (unsigned*)p; p += EKG;
    int2* ui_iw  = (int2*)p;    p += (long)EIN * 2;
    int2* ui_tmp = (int2*)p;    p += (long)EIN * 2;
    int2* iu_iw  = (int2*)p;    p += (long)EIN * 2;
    int2* iu_tmp = (int2*)p;    p += (long)EIN * 2;

    const int B = 256;

    // ---- init: zero accumulators + bucket counters; fp16 mirrors ----
    hipMemsetAsync(eacc, 0, (size_t)(NE + NU) * DIM * 4, stream);
    hipMemsetAsync(cntK, 0, (size_t)768 * 4, stream);
    k_castH<<<(NE * DIM + B - 1) / B, B, 0, stream>>>(ent0, usr0, relf, entHa, usrHa, relH);

    // ---- CSR build ----
    k_hist_bucket<<<512, 256, 0, stream>>>(eh, iu, ii, cntK, cntU, cntI);
    k_bucket_scan<<<1, 256, 0, stream>>>(cntK, cntU, cntI, kg_boff, ui_boff, iu_boff,
                                         kg_g, ui_g, iu_g);
    k_binB_kg<<<(EKG + KG_CHUNK - 1) / KG_CHUNK, 256, 0, stream>>>(eh, et, etype, kg_g, kg_tmp);
    k_binB8<<<(EIN + B8_CHUNK - 1) / B8_CHUNK, 256, 0, stream>>>(iu, ii, iwf, EIN, 8, 17, ui_g, ui_tmp);
    k_binB8<<<(EIN + B8_CHUNK - 1) / B8_CHUNK, 256, 0, stream>>>(ii, iu, iwf, EIN, 9, 16, iu_g, iu_tmp);
    k_binC_kg<<<KG_NBUCK, 256, 0, stream>>>(kg_tmp, kg_boff, kg_tr, kg_off);
    k_binC8<<<(NU + 255) >> 8, 256, 0, stream>>>(ui_tmp, ui_boff, ui_iw, ui_off, NU, 8, 17);
    k_binC8<<<(NE + 511) >> 9, 256, 0, stream>>>(iu_tmp, iu_boff, iu_iw, iu_off, NE, 9, 16);

    // ---- layer 0 ----
    k_gemm_f<<<NE / 4, 256, 0, stream>>>(ent0, wqf, qmH, NE);
    k_ent<<<(NE + 3) / 4, 256, 0, stream>>>(qmH, relH, entHa, usrHa,
                                            kg_off, kg_tr, iu_off, iu_iw, eacc, entHb);
    k_usr<<<(NU + 3) / 4, 256, 0, stream>>>(entHa, ui_off, ui_iw, uacc, usrHb);
    // ---- layer 1 ----
    k_gemm_h<<<NE / 4, 256, 0, stream>>>(entHb, wqf, qmH, NE);
    k_ent<<<(NE + 3) / 4, 256, 0, stream>>>(qmH, relH, entHb, usrHb,
                                            kg_off, kg_tr, iu_off, iu_iw, eacc, entHa);
    k_usr<<<(NU + 3) / 4, 256, 0, stream>>>(entHb, ui_off, ui_iw, uacc, usrHa);

    k_final<<<((NU + NE) * DIM + B - 1) / B, B, 0, stream>>>(usr0, uacc, ent0, eacc, out);
}

// Round 5
// 604.713 us; speedup vs baseline: 1.3183x; 1.0246x over previous
//
#include <hip/hip_runtime.h>
#include <hip/hip_fp16.h>

#define NU 50000
#define NE 100000
#define DIM 64
#define NRELS 16
#define EKG 1500000
#define EIN 1000000

#define KG_CHUNK 8192
#define KG_NBUCK ((NE + 511) >> 9)   // 196
#define B8_CHUNK 4096
#define KG_CAP 9216                  // Binomial mean 7680, sigma 87 -> +17s
#define C8_CAP 6656                  // mean 5120, sigma 71 -> +21s

#define NEB (NE / 4)                 // 25000 ent blocks
#define NUB (NU / 4)                 // 12500 usr blocks

typedef _Float16 f16x2 __attribute__((ext_vector_type(2)));

union U16 { int4 v; __half2 h[4]; };

__device__ __forceinline__ float fdot2a(__half2 a, __half2 b, float c) {
#if __has_builtin(__builtin_amdgcn_fdot2)
    union { __half2 h; f16x2 v; } ua, ub;
    ua.h = a; ub.h = b;
    return __builtin_amdgcn_fdot2(ua.v, ub.v, c, false);
#else
    return c + __half2float(a.x) * __half2float(b.x) + __half2float(a.y) * __half2float(b.y);
#endif
}

// sum over each 4-lane quad via DPP (score reduce; head = quad)
__device__ __forceinline__ float dpp_red4(float p) {
    int t;
    t = __builtin_amdgcn_update_dpp(0, __float_as_int(p), 0xB1, 0xF, 0xF, true);  // quad_perm xor1
    p += __int_as_float(t);
    t = __builtin_amdgcn_update_dpp(0, __float_as_int(p), 0x4E, 0xF, 0xF, true);  // quad_perm xor2
    p += __int_as_float(t);
    return p;
}

// fp16 mirror cast for layer-0 inputs + rel table
__global__ void k_castH(const float* __restrict__ ent0, const float* __restrict__ usr0,
                        const float* __restrict__ relf,
                        __half* __restrict__ entH, __half* __restrict__ usrH,
                        __half* __restrict__ relH) {
    int i = blockIdx.x * blockDim.x + threadIdx.x;
    if (i < NE * DIM) entH[i] = __float2half(ent0[i]);
    if (i < NU * DIM) usrH[i] = __float2half(usr0[i]);
    if (i < NRELS * DIM) relH[i] = __float2half(relf[i]);
}

// qmH[i][c] = (half) sum_k ent[i][k] * WQ[k][c]  -- f32 input
__global__ __launch_bounds__(256) void k_gemm_f(const float* __restrict__ ent,
                                                const float* __restrict__ wq,
                                                __half* __restrict__ qmH, int nrows) {
    __shared__ float sW[64 * 64];
    __shared__ float sR[4][64];
    int t = threadIdx.x;
    for (int i = t; i < 4096; i += 256) sW[i] = wq[i];
    int r = t >> 6, c = t & 63;
    int row = blockIdx.x * 4 + r;
    sR[r][c] = (row < nrows) ? ent[row * 64 + c] : 0.f;
    __syncthreads();
    float acc = 0.f;
#pragma unroll
    for (int k = 0; k < 64; k++) acc += sR[r][k] * sW[k * 64 + c];
    if (row < nrows) qmH[row * 64 + c] = __float2half(acc);
}

// same, fp16 input
__global__ __launch_bounds__(256) void k_gemm_h(const __half* __restrict__ ent,
                                                const float* __restrict__ wq,
                                                __half* __restrict__ qmH, int nrows) {
    __shared__ float sW[64 * 64];
    __shared__ float sR[4][64];
    int t = threadIdx.x;
    for (int i = t; i < 4096; i += 256) sW[i] = wq[i];
    int r = t >> 6, c = t & 63;
    int row = blockIdx.x * 4 + r;
    sR[r][c] = (row < nrows) ? __half2float(ent[row * 64 + c]) : 0.f;
    __syncthreads();
    float acc = 0.f;
#pragma unroll
    for (int k = 0; k < 64; k++) acc += sR[r][k] * sW[k * 64 + c];
    if (row < nrows) qmH[row * 64 + c] = __float2half(acc);
}

// ---- bucket-level histogram (LDS-privatized) ----
__global__ __launch_bounds__(256) void k_hist_bucket(const int* __restrict__ eh,
        const int* __restrict__ iu, const int* __restrict__ ii,
        int* __restrict__ cntK, int* __restrict__ cntU, int* __restrict__ cntI) {
    __shared__ int sK[256], sU[256], sI[256];
    int t = threadIdx.x;
    sK[t] = 0; sU[t] = 0; sI[t] = 0;
    __syncthreads();
    int stride = gridDim.x * 256;
    for (int e = blockIdx.x * 256 + t; e < EKG; e += stride)
        atomicAdd(&sK[eh[e] >> 9], 1);
    for (int e = blockIdx.x * 256 + t; e < EIN; e += stride) {
        atomicAdd(&sU[iu[e] >> 8], 1);
        atomicAdd(&sI[ii[e] >> 9], 1);
    }
    __syncthreads();
    if (sK[t]) atomicAdd(&cntK[t], sK[t]);
    if (sU[t]) atomicAdd(&cntU[t], sU[t]);
    if (sI[t]) atomicAdd(&cntI[t], sI[t]);
}

// ---- tiny scans: bucket counts -> bucket offsets + gcur init ----
__global__ __launch_bounds__(256) void k_bucket_scan(const int* __restrict__ cntK,
        const int* __restrict__ cntU, const int* __restrict__ cntI,
        int* __restrict__ kg_boff, int* __restrict__ ui_boff, int* __restrict__ iu_boff,
        int* __restrict__ kg_g, int* __restrict__ ui_g, int* __restrict__ iu_g) {
    __shared__ int sc[256];
    int t = threadIdx.x;
#define SCAN1(cnt, boff, gcur) { \
    int v = cnt[t]; sc[t] = v; __syncthreads(); \
    for (int o = 1; o < 256; o <<= 1) { \
        int u = (t >= o) ? sc[t - o] : 0; __syncthreads(); sc[t] += u; __syncthreads(); } \
    int e = sc[t] - v; boff[t] = e; gcur[t] = e; \
    __syncthreads(); }
    SCAN1(cntK, kg_boff, kg_g)
    SCAN1(cntU, ui_boff, ui_g)
    SCAN1(cntI, iu_boff, iu_g)
#undef SCAN1
}

// ---- pass B: bin KG edges into node-range buckets (LDS staged, coalesced flush)
__global__ __launch_bounds__(256) void k_binB_kg(const int* __restrict__ eh,
        const int* __restrict__ et, const int* __restrict__ ety,
        int* __restrict__ gcur, unsigned* __restrict__ tmp) {
    __shared__ unsigned stage[KG_CHUNK];
    __shared__ int dest[KG_CHUNK];
    __shared__ int cnt[KG_NBUCK], boff[KG_NBUCK], gbase[KG_NBUCK], curl[KG_NBUCK];
    __shared__ int sc[256];
    int t = threadIdx.x;
    int base = blockIdx.x * KG_CHUNK;
    int nloc = EKG - base; if (nloc > KG_CHUNK) nloc = KG_CHUNK;
    for (int i = t; i < KG_NBUCK; i += 256) cnt[i] = 0;
    __syncthreads();
    for (int i = t; i < nloc; i += 256)
        atomicAdd(&cnt[eh[base + i] >> 9], 1);
    __syncthreads();
    int v = (t < KG_NBUCK) ? cnt[t] : 0;
    sc[t] = v;
    __syncthreads();
    for (int o = 1; o < 256; o <<= 1) {
        int u = (t >= o) ? sc[t - o] : 0;
        __syncthreads();
        sc[t] += u;
        __syncthreads();
    }
    if (t < KG_NBUCK) {
        boff[t] = sc[t] - v;
        curl[t] = sc[t] - v;
        gbase[t] = atomicAdd(&gcur[t], v);
    }
    __syncthreads();
    for (int i = t; i < nloc; i += 256) {
        int e = base + i;
        int h = eh[e];
        int b = h >> 9;
        unsigned pay = (unsigned)et[e] | ((unsigned)(ety[e] - 1) << 17)
                     | ((unsigned)(h & 511) << 21);
        int pos = atomicAdd(&curl[b], 1);
        stage[pos] = pay;
        dest[pos] = gbase[b] + (pos - boff[b]);
    }
    __syncthreads();
    for (int s = t; s < nloc; s += 256) tmp[dest[s]] = stage[s];
}

// ---- pass B generic, 8B payload {aux|low<<auxShift, w}
__global__ __launch_bounds__(256) void k_binB8(const int* __restrict__ key,
        const int* __restrict__ aux, const float* __restrict__ wv, int nE,
        int shift, int auxShift, int* __restrict__ gcur, int2* __restrict__ tmp) {
    __shared__ int2 stage[B8_CHUNK];
    __shared__ int dest[B8_CHUNK];
    __shared__ int cnt[256], boff[256], gbase[256], curl[256];
    __shared__ int sc[256];
    int t = threadIdx.x;
    int base = blockIdx.x * B8_CHUNK;
    int nloc = nE - base; if (nloc > B8_CHUNK) nloc = B8_CHUNK;
    cnt[t] = 0;
    __syncthreads();
    for (int i = t; i < nloc; i += 256)
        atomicAdd(&cnt[key[base + i] >> shift], 1);
    __syncthreads();
    int v = cnt[t];
    sc[t] = v;
    __syncthreads();
    for (int o = 1; o < 256; o <<= 1) {
        int u = (t >= o) ? sc[t - o] : 0;
        __syncthreads();
        sc[t] += u;
        __syncthreads();
    }
    boff[t] = sc[t] - v;
    curl[t] = sc[t] - v;
    gbase[t] = atomicAdd(&gcur[t], v);
    __syncthreads();
    int lowmask = (1 << shift) - 1;
    for (int i = t; i < nloc; i += 256) {
        int e = base + i;
        int k = key[e];
        int b = k >> shift;
        int2 pay;
        pay.x = aux[e] | ((k & lowmask) << auxShift);
        pay.y = __float_as_int(wv[e]);
        int pos = atomicAdd(&curl[b], 1);
        stage[pos] = pay;
        dest[pos] = gbase[b] + (pos - boff[b]);
    }
    __syncthreads();
    for (int s = t; s < nloc; s += 256) tmp[dest[s]] = stage[s];
}

// ---- pass C: within-bucket counting sort into final CSR; writes per-node offsets
__global__ __launch_bounds__(256) void k_binC_kg(const unsigned* __restrict__ tmp,
        const int* __restrict__ boff, unsigned* __restrict__ dst,
        int* __restrict__ off) {
    __shared__ unsigned stage[KG_CAP];
    __shared__ int curl[512];
    __shared__ int sc[256];
    int b = blockIdx.x;
    int nbase = b << 9;
    int nlim = NE - nbase; if (nlim > 512) nlim = 512;
    if (nlim <= 0) return;
    int t = threadIdx.x;
    int r0 = boff[b];
    int r1 = boff[b + 1];
    int cntb = r1 - r0;
    curl[t] = 0; curl[t + 256] = 0;
    __syncthreads();
    for (int s = t; s < cntb; s += 256)
        atomicAdd(&curl[(tmp[r0 + s] >> 21) & 511], 1);
    __syncthreads();
    int v0 = curl[2 * t], v1 = curl[2 * t + 1];
    int s2 = v0 + v1;
    sc[t] = s2;
    __syncthreads();
    for (int o = 1; o < 256; o <<= 1) {
        int u = (t >= o) ? sc[t - o] : 0;
        __syncthreads();
        sc[t] += u;
        __syncthreads();
    }
    int excl = sc[t] - s2;
    curl[2 * t] = excl;
    curl[2 * t + 1] = excl + v0;
    if (2 * t < nlim) off[nbase + 2 * t] = r0 + excl;
    if (2 * t + 1 < nlim) off[nbase + 2 * t + 1] = r0 + excl + v0;
    if (b == KG_NBUCK - 1 && t == 0) off[nbase + nlim] = r1;   // sentinel off[NE]
    __syncthreads();
    if (cntb <= KG_CAP) {
        for (int s = t; s < cntb; s += 256) {
            unsigned pay = tmp[r0 + s];
            int l = (pay >> 21) & 511;
            int pos = atomicAdd(&curl[l], 1);
            stage[pos] = pay;
        }
        __syncthreads();
        for (int s = t; s < cntb; s += 256) dst[r0 + s] = stage[s];
    } else {
        for (int s = t; s < cntb; s += 256) {
            unsigned pay = tmp[r0 + s];
            int l = (pay >> 21) & 511;
            int pos = atomicAdd(&curl[l], 1);
            dst[r0 + pos] = pay;
        }
    }
}

__global__ __launch_bounds__(256) void k_binC8(const int2* __restrict__ tmp,
        const int* __restrict__ boff, int2* __restrict__ dst,
        int* __restrict__ off, int nnodes, int shift, int auxShift) {
    __shared__ int2 stage[C8_CAP];
    __shared__ int curl[512];
    __shared__ int sc[256];
    int b = blockIdx.x;
    int nbase = b << shift;
    int nlim = nnodes - nbase; if (nlim > (1 << shift)) nlim = 1 << shift;
    if (nlim <= 0) return;
    int t = threadIdx.x;
    int r0 = boff[b];
    int r1 = boff[b + 1];
    int cntb = r1 - r0;
    int lowmask = (1 << shift) - 1;
    curl[t] = 0; curl[t + 256] = 0;
    __syncthreads();
    for (int s = t; s < cntb; s += 256)
        atomicAdd(&curl[(tmp[r0 + s].x >> auxShift) & lowmask], 1);
    __syncthreads();
    int v0 = curl[2 * t], v1 = curl[2 * t + 1];
    int s2 = v0 + v1;
    sc[t] = s2;
    __syncthreads();
    for (int o = 1; o < 256; o <<= 1) {
        int u = (t >= o) ? sc[t - o] : 0;
        __syncthreads();
        sc[t] += u;
        __syncthreads();
    }
    int excl = sc[t] - s2;
    curl[2 * t] = excl;
    curl[2 * t + 1] = excl + v0;
    if (2 * t < nlim) off[nbase + 2 * t] = r0 + excl;
    if (2 * t + 1 < nlim) off[nbase + 2 * t + 1] = r0 + excl + v0;
    if (b == gridDim.x - 1 && t == 0) off[nbase + nlim] = r1;  // sentinel
    __syncthreads();
    if (cntb <= C8_CAP) {
        for (int s = t; s < cntb; s += 256) {
            int2 pay = tmp[r0 + s];
            int l = (pay.x >> auxShift) & lowmask;
            int pos = atomicAdd(&curl[l], 1);
            stage[pos] = pay;
        }
        __syncthreads();
        for (int s = t; s < cntb; s += 256) dst[r0 + s] = stage[s];
    } else {
        for (int s = t; s < cntb; s += 256) {
            int2 pay = tmp[r0 + s];
            int l = (pay.x >> auxShift) & lowmask;
            int pos = atomicAdd(&curl[l], 1);
            dst[r0 + pos] = pay;
        }
    }
}

// ---- fused per-layer kernel: blocks [0,NEB) entity aggregation, [NEB,NEB+NUB) users.
// Inner loops are bit-identical to the R3 passing k_ent/k_usr (8 lanes/edge,
// 8 edges/step, payload prefetch 1 step ahead, direct __expf, cvt+fma accumulate).
__global__ __launch_bounds__(256) void k_layer(const __half* __restrict__ qmH,
        const __half* __restrict__ relH, const __half* __restrict__ entH,
        const __half* __restrict__ usrH,
        const int* __restrict__ kg_off, const unsigned* __restrict__ kg_tr,
        const int* __restrict__ iu_off, const int2* __restrict__ iu_iw,
        const int* __restrict__ ui_off, const int2* __restrict__ ui_iw,
        float* __restrict__ eacc, __half* __restrict__ entHout,
        float* __restrict__ uacc, __half* __restrict__ usrHout) {
    int w = __builtin_amdgcn_readfirstlane(threadIdx.x >> 6);
    int lane = threadIdx.x & 63;
    int sub = lane >> 3;          // edge slot 0..7
    int li  = lane & 7;           // dims 8li..8li+7
    const float SC = 0.17677669529663687f; // 1/sqrt(32)
    const float NEG = -1e30f;
    const int4* qmI  = (const int4*)qmH;
    const int4* entI = (const int4*)entH;
    const int4* relI = (const int4*)relH;
    const int4* usrI = (const int4*)usrH;

    if (blockIdx.x < NEB) {
        // ================= entity path (R3 k_ent body) =================
        int node = blockIdx.x * 4 + w;
        U16 qh; qh.v = qmI[(long)node * 8 + li];
        int b0 = kg_off[node], b1 = kg_off[node + 1];
        int deg = b1 - b0;

        float ssum = 0.f;
        float acc[8] = {0.f, 0.f, 0.f, 0.f, 0.f, 0.f, 0.f, 0.f};
        if (deg > 0) {
            int s = b0;
            int i0 = s + sub;
            unsigned tr = kg_tr[i0 < b1 ? i0 : b1 - 1];
            for (; s < b1; s += 8) {
                int ni = s + 8 + sub;
                unsigned trn = kg_tr[ni < b1 ? ni : b1 - 1];  // prefetch next step's payload
                bool has = (s + sub) < b1;
                int tl = tr & 0x1FFFF, rr = (tr >> 17) & 15;
                U16 rl; rl.v = relI[rr * 8 + li];
                U16 qt; qt.v = qmI[(long)tl * 8 + li];
                U16 ev; ev.v = entI[(long)tl * 8 + li];
                float p = 0.f;
#pragma unroll
                for (int k = 0; k < 4; k++) {
                    __half2 kk = __hmul2(qt.h[k], rl.h[k]);
                    p = fdot2a(qh.h[k], kk, p);
                }
                p = dpp_red4(p);
                float e = __expf(has ? p * SC : NEG);
                ssum += e;
#pragma unroll
                for (int k = 0; k < 4; k++) {
                    __half2 v2 = __hmul2(ev.h[k], rl.h[k]);
                    float2 vf = __half22float2(v2);
                    acc[2 * k]     += vf.x * e;
                    acc[2 * k + 1] += vf.y * e;
                }
                tr = trn;
            }
#pragma unroll
            for (int o = 8; o <= 32; o <<= 1) {
                ssum += __shfl_xor(ssum, o, 64);
#pragma unroll
                for (int k = 0; k < 8; k++) acc[k] += __shfl_xor(acc[k], o, 64);
            }
            float inv = 1.f / ssum;
#pragma unroll
            for (int k = 0; k < 8; k++) acc[k] *= inv;
            float ss = 0.f;
#pragma unroll
            for (int k = 0; k < 8; k++) ss += acc[k] * acc[k];
            ss += __shfl_xor(ss, 1, 64);
            ss += __shfl_xor(ss, 2, 64);
            ss += __shfl_xor(ss, 4, 64);
            float nsc = 1.f / fmaxf(sqrtf(ss), 1e-12f);
#pragma unroll
            for (int k = 0; k < 8; k++) acc[k] *= nsc;
        }

        // user -> entity gather (R3 body)
        int c0 = iu_off[node], c1 = iu_off[node + 1];
        if (c1 > c0) {
            float ua[8] = {0.f, 0.f, 0.f, 0.f, 0.f, 0.f, 0.f, 0.f};
            int t2 = c0;
            int j0 = t2 + sub;
            int2 pw = iu_iw[j0 < c1 ? j0 : c1 - 1];
            for (; t2 < c1; t2 += 8) {
                int nj = t2 + 8 + sub;
                int2 pwn = iu_iw[nj < c1 ? nj : c1 - 1];
                bool has = (t2 + sub) < c1;
                float wv = has ? __int_as_float(pw.y) : 0.f;
                U16 uu; uu.v = usrI[(long)(pw.x & 0xFFFF) * 8 + li];
#pragma unroll
                for (int k = 0; k < 4; k++) {
                    float2 uf = __half22float2(uu.h[k]);
                    ua[2 * k]     += wv * uf.x;
                    ua[2 * k + 1] += wv * uf.y;
                }
                pw = pwn;
            }
#pragma unroll
            for (int o = 8; o <= 32; o <<= 1) {
#pragma unroll
                for (int k = 0; k < 8; k++) ua[k] += __shfl_xor(ua[k], o, 64);
            }
#pragma unroll
            for (int k = 0; k < 8; k++) acc[k] += ua[k];
        }

        if (sub == 0) {
            long base = (long)node * 16 + 2 * li;
            float4* eacc4 = (float4*)eacc;
            float4 e0 = eacc4[base], e1 = eacc4[base + 1];
            e0.x += acc[0]; e0.y += acc[1]; e0.z += acc[2]; e0.w += acc[3];
            e1.x += acc[4]; e1.y += acc[5]; e1.z += acc[6]; e1.w += acc[7];
            eacc4[base] = e0; eacc4[base + 1] = e1;
            U16 ho;
            ho.h[0] = __floats2half2_rn(acc[0], acc[1]);
            ho.h[1] = __floats2half2_rn(acc[2], acc[3]);
            ho.h[2] = __floats2half2_rn(acc[4], acc[5]);
            ho.h[3] = __floats2half2_rn(acc[6], acc[7]);
            ((int4*)entHout)[(long)node * 8 + li] = ho.v;
        }
    } else {
        // ================= user path (R3 k_usr body) =================
        int node = (blockIdx.x - NEB) * 4 + w;
        int b0 = ui_off[node], b1 = ui_off[node + 1];
        float ax[8] = {0.f, 0.f, 0.f, 0.f, 0.f, 0.f, 0.f, 0.f};
        if (b1 > b0) {
            int s = b0;
            int j0 = s + sub;
            int2 pw = ui_iw[j0 < b1 ? j0 : b1 - 1];
            for (; s < b1; s += 8) {
                int nj = s + 8 + sub;
                int2 pwn = ui_iw[nj < b1 ? nj : b1 - 1];
                bool has = (s + sub) < b1;
                float wv = has ? __int_as_float(pw.y) : 0.f;
                U16 uu; uu.v = entI[(long)(pw.x & 0x1FFFF) * 8 + li];
#pragma unroll
                for (int k = 0; k < 4; k++) {
                    float2 uf = __half22float2(uu.h[k]);
                    ax[2 * k]     += wv * uf.x;
                    ax[2 * k + 1] += wv * uf.y;
                }
                pw = pwn;
            }
#pragma unroll
            for (int o = 8; o <= 32; o <<= 1) {
#pragma unroll
                for (int k = 0; k < 8; k++) ax[k] += __shfl_xor(ax[k], o, 64);
            }
        }
        if (sub == 0) {
            long base = (long)node * 16 + 2 * li;
            float4* uacc4 = (float4*)uacc;
            float4 u0 = uacc4[base], u1 = uacc4[base + 1];
            u0.x += ax[0]; u0.y += ax[1]; u0.z += ax[2]; u0.w += ax[3];
            u1.x += ax[4]; u1.y += ax[5]; u1.z += ax[6]; u1.w += ax[7];
            uacc4[base] = u0; uacc4[base + 1] = u1;
            U16 ho;
            ho.h[0] = __floats2half2_rn(ax[0], ax[1]);
            ho.h[1] = __floats2half2_rn(ax[2], ax[3]);
            ho.h[2] = __floats2half2_rn(ax[4], ax[5]);
            ho.h[3] = __floats2half2_rn(ax[6], ax[7]);
            ((int4*)usrHout)[(long)node * 8 + li] = ho.v;
        }
    }
}

// out = concat((usr0 + uacc)/3, (ent0 + eacc)/3)
__global__ void k_final(const float* __restrict__ usr0, const float* __restrict__ uacc,
                        const float* __restrict__ ent0, const float* __restrict__ eacc,
                        float* __restrict__ out) {
    int i = blockIdx.x * blockDim.x + threadIdx.x;
    const float inv3 = 1.f / 3.f;
    if (i < NU * DIM) {
        out[i] = (usr0[i] + uacc[i]) * inv3;
    } else if (i < (NU + NE) * DIM) {
        int j = i - NU * DIM;
        out[i] = (ent0[j] + eacc[j]) * inv3;
    }
}

extern "C" void kernel_launch(void* const* d_in, const int* in_sizes, int n_in,
                              void* d_out, int out_size, void* d_ws, size_t ws_size,
                              hipStream_t stream) {
    const float* usr0  = (const float*)d_in[1];
    const float* ent0  = (const float*)d_in[2];
    const int*   inter = (const int*)d_in[3];
    const float* iwf   = (const float*)d_in[4];
    const int*   eidx  = (const int*)d_in[5];
    const int*   etype = (const int*)d_in[6];
    const float* relf  = (const float*)d_in[7];
    const float* wqf   = (const float*)d_in[8];
    float* out = (float*)d_out;

    const int* eh = eidx;
    const int* et = eidx + EKG;
    const int* iu = inter;
    const int* ii = inter + EIN;

    // ---- workspace layout (4B words) ----
    float* p = (float*)d_ws;
    float* eacc = p;  p += (long)NE * DIM;        // contiguous accs -> one memset
    float* uacc = p;  p += (long)NU * DIM;
    __half* qmH   = (__half*)p;  p += (long)NE * DIM / 2;
    __half* entHa = (__half*)p;  p += (long)NE * DIM / 2;
    __half* entHb = (__half*)p;  p += (long)NE * DIM / 2;
    __half* usrHa = (__half*)p;  p += (long)NU * DIM / 2;
    __half* usrHb = (__half*)p;  p += (long)NU * DIM / 2;
    __half* relH  = (__half*)p;  p += (long)NRELS * DIM / 2;
    int* cntK = (int*)p;        p += 256;         // bucket counts (contiguous -> one memset)
    int* cntU = (int*)p;        p += 256;
    int* cntI = (int*)p;        p += 256;
    int* kg_boff = (int*)p;     p += 256;         // bucket offsets (pristine)
    int* ui_boff = (int*)p;     p += 256;
    int* iu_boff = (int*)p;     p += 256;
    int* kg_off = (int*)p;      p += NE + 2;      // per-node CSR offsets (written by pass C)
    int* ui_off = (int*)p;      p += NU + 2;
    int* iu_off = (int*)p;      p += NE + 2;
    int* kg_g   = (int*)p;      p += 256;         // pass-B reservation cursors
    int* ui_g   = (int*)p;      p += 256;
    int* iu_g   = (int*)p;      p += 256;
    unsigned* kg_tr  = (unsigned*)p; p += EKG;
    unsigned* kg_tmp = (unsigned*)p; p += EKG;
    int2* ui_iw  = (int2*)p;    p += (long)EIN * 2;
    int2* ui_tmp = (int2*)p;    p += (long)EIN * 2;
    int2* iu_iw  = (int2*)p;    p += (long)EIN * 2;
    int2* iu_tmp = (int2*)p;    p += (long)EIN * 2;

    const int B = 256;

    // ---- init: zero accumulators + bucket counters; fp16 mirrors ----
    hipMemsetAsync(eacc, 0, (size_t)(NE + NU) * DIM * 4, stream);
    hipMemsetAsync(cntK, 0, (size_t)768 * 4, stream);
    k_castH<<<(NE * DIM + B - 1) / B, B, 0, stream>>>(ent0, usr0, relf, entHa, usrHa, relH);

    // ---- CSR build ----
    k_hist_bucket<<<512, 256, 0, stream>>>(eh, iu, ii, cntK, cntU, cntI);
    k_bucket_scan<<<1, 256, 0, stream>>>(cntK, cntU, cntI, kg_boff, ui_boff, iu_boff,
                                         kg_g, ui_g, iu_g);
    k_binB_kg<<<(EKG + KG_CHUNK - 1) / KG_CHUNK, 256, 0, stream>>>(eh, et, etype, kg_g, kg_tmp);
    k_binB8<<<(EIN + B8_CHUNK - 1) / B8_CHUNK, 256, 0, stream>>>(iu, ii, iwf, EIN, 8, 17, ui_g, ui_tmp);
    k_binB8<<<(EIN + B8_CHUNK - 1) / B8_CHUNK, 256, 0, stream>>>(ii, iu, iwf, EIN, 9, 16, iu_g, iu_tmp);
    k_binC_kg<<<KG_NBUCK, 256, 0, stream>>>(kg_tmp, kg_boff, kg_tr, kg_off);
    k_binC8<<<(NU + 255) >> 8, 256, 0, stream>>>(ui_tmp, ui_boff, ui_iw, ui_off, NU, 8, 17);
    k_binC8<<<(NE + 511) >> 9, 256, 0, stream>>>(iu_tmp, iu_boff, iu_iw, iu_off, NE, 9, 16);

    // ---- layer 0 ----
    k_gemm_f<<<NE / 4, 256, 0, stream>>>(ent0, wqf, qmH, NE);
    k_layer<<<NEB + NUB, 256, 0, stream>>>(qmH, relH, entHa, usrHa,
                                           kg_off, kg_tr, iu_off, iu_iw, ui_off, ui_iw,
                                           eacc, entHb, uacc, usrHb);
    // ---- layer 1 ----
    k_gemm_h<<<NE / 4, 256, 0, stream>>>(entHb, wqf, qmH, NE);
    k_layer<<<NEB + NUB, 256, 0, stream>>>(qmH, relH, entHb, usrHb,
                                           kg_off, kg_tr, iu_off, iu_iw, ui_off, ui_iw,
                                           eacc, entHa, uacc, usrHa);

    k_final<<<((NU + NE) * DIM + B - 1) / B, B, 0, stream>>>(usr0, uacc, ent0, eacc, out);
}

// Round 6
// 490.595 us; speedup vs baseline: 1.6249x; 1.2326x over previous
//
#include <hip/hip_runtime.h>
#include <hip/hip_fp16.h>

#define NU 50000
#define NE 100000
#define DIM 64
#define NRELS 16
#define EKG 1500000
#define EIN 1000000

#define KG_CHUNK 8192
#define KG_NBUCK ((NE + 511) >> 9)   // 196
#define B8_CHUNK 4096
#define KG_CAP 9216                  // Binomial mean 7680, sigma 87 -> +17s
#define C8_CAP 6656                  // mean 5120, sigma 71 -> +21s

#define NEB (NE / 4)                 // 25000 ent blocks
#define NUB (NU / 4)                 // 12500 usr blocks

#define NB_BKG ((EKG + KG_CHUNK - 1) / KG_CHUNK)   // 184
#define NB_B8  ((EIN + B8_CHUNK - 1) / B8_CHUNK)   // 245
#define NB_CKG KG_NBUCK                             // 196
#define NB_CUI ((NU + 255) >> 8)                    // 196
#define NB_CIU ((NE + 511) >> 9)                    // 196

typedef _Float16 f16x2 __attribute__((ext_vector_type(2)));

union U16 { int4 v; __half2 h[4]; };
union H4 { int2 i2; __half2 h[2]; };

__device__ __forceinline__ float fdot2a(__half2 a, __half2 b, float c) {
#if __has_builtin(__builtin_amdgcn_fdot2)
    union { __half2 h; f16x2 v; } ua, ub;
    ua.h = a; ub.h = b;
    return __builtin_amdgcn_fdot2(ua.v, ub.v, c, false);
#else
    return c + __half2float(a.x) * __half2float(b.x) + __half2float(a.y) * __half2float(b.y);
#endif
}

// sum over each 4-lane quad via DPP (score reduce; head = quad)
__device__ __forceinline__ float dpp_red4(float p) {
    int t;
    t = __builtin_amdgcn_update_dpp(0, __float_as_int(p), 0xB1, 0xF, 0xF, true);  // quad_perm xor1
    p += __int_as_float(t);
    t = __builtin_amdgcn_update_dpp(0, __float_as_int(p), 0x4E, 0xF, 0xF, true);  // quad_perm xor2
    p += __int_as_float(t);
    return p;
}

// fp16 mirror cast for layer-0 inputs + rel table (vectorized: float4 -> 4 halfs)
__global__ void k_castH(const float4* __restrict__ e4, const float4* __restrict__ u4,
                        const float4* __restrict__ r4,
                        int2* __restrict__ eH, int2* __restrict__ uH, int2* __restrict__ rH) {
    int i = blockIdx.x * blockDim.x + threadIdx.x;
    if (i < NE * 16) {
        float4 v = e4[i];
        H4 o; o.h[0] = __floats2half2_rn(v.x, v.y); o.h[1] = __floats2half2_rn(v.z, v.w);
        eH[i] = o.i2;
    }
    if (i < NU * 16) {
        float4 v = u4[i];
        H4 o; o.h[0] = __floats2half2_rn(v.x, v.y); o.h[1] = __floats2half2_rn(v.z, v.w);
        uH[i] = o.i2;
    }
    if (i < NRELS * 16) {
        float4 v = r4[i];
        H4 o; o.h[0] = __floats2half2_rn(v.x, v.y); o.h[1] = __floats2half2_rn(v.z, v.w);
        rH[i] = o.i2;
    }
}

// qm = ent @ WQ -> fp16. 16 rows/block, thread = 1 row x 4 cols (float4 W reads).
__global__ __launch_bounds__(256) void k_gemm_f(const float* __restrict__ ent,
                                                const float* __restrict__ wq,
                                                __half* __restrict__ qmH) {
    __shared__ float sW[64 * 64];
    __shared__ float sR[16 * 64];
    int t = threadIdx.x;
    for (int i = t; i < 4096; i += 256) sW[i] = wq[i];
    long row0 = (long)blockIdx.x * 16;
    for (int i = t; i < 1024; i += 256) sR[i] = ent[row0 * 64 + i];
    __syncthreads();
    int r = t >> 4, cg = t & 15;
    const float4* sW4 = (const float4*)sW;
    float4 acc = {0.f, 0.f, 0.f, 0.f};
#pragma unroll
    for (int k = 0; k < 64; k++) {
        float a = sR[r * 64 + k];
        float4 wv = sW4[k * 16 + cg];
        acc.x += a * wv.x; acc.y += a * wv.y; acc.z += a * wv.z; acc.w += a * wv.w;
    }
    H4 o;
    o.h[0] = __floats2half2_rn(acc.x, acc.y);
    o.h[1] = __floats2half2_rn(acc.z, acc.w);
    ((int2*)qmH)[(row0 + r) * 16 + cg] = o.i2;
}

// same, fp16 input
__global__ __launch_bounds__(256) void k_gemm_h(const __half* __restrict__ ent,
                                                const float* __restrict__ wq,
                                                __half* __restrict__ qmH) {
    __shared__ float sW[64 * 64];
    __shared__ float sR[16 * 64];
    int t = threadIdx.x;
    for (int i = t; i < 4096; i += 256) sW[i] = wq[i];
    long row0 = (long)blockIdx.x * 16;
    const __half2* e2 = (const __half2*)ent;
    for (int i = t; i < 512; i += 256) {
        float2 f = __half22float2(e2[row0 * 32 + i]);
        sR[2 * i] = f.x; sR[2 * i + 1] = f.y;
    }
    __syncthreads();
    int r = t >> 4, cg = t & 15;
    const float4* sW4 = (const float4*)sW;
    float4 acc = {0.f, 0.f, 0.f, 0.f};
#pragma unroll
    for (int k = 0; k < 64; k++) {
        float a = sR[r * 64 + k];
        float4 wv = sW4[k * 16 + cg];
        acc.x += a * wv.x; acc.y += a * wv.y; acc.z += a * wv.z; acc.w += a * wv.w;
    }
    H4 o;
    o.h[0] = __floats2half2_rn(acc.x, acc.y);
    o.h[1] = __floats2half2_rn(acc.z, acc.w);
    ((int2*)qmH)[(row0 + r) * 16 + cg] = o.i2;
}

// ---- bucket-level histogram (LDS-privatized) ----
__global__ __launch_bounds__(256) void k_hist_bucket(const int* __restrict__ eh,
        const int* __restrict__ iu, const int* __restrict__ ii,
        int* __restrict__ cntK, int* __restrict__ cntU, int* __restrict__ cntI) {
    __shared__ int sK[256], sU[256], sI[256];
    int t = threadIdx.x;
    sK[t] = 0; sU[t] = 0; sI[t] = 0;
    __syncthreads();
    int stride = gridDim.x * 256;
    for (int e = blockIdx.x * 256 + t; e < EKG; e += stride)
        atomicAdd(&sK[eh[e] >> 9], 1);
    for (int e = blockIdx.x * 256 + t; e < EIN; e += stride) {
        atomicAdd(&sU[iu[e] >> 8], 1);
        atomicAdd(&sI[ii[e] >> 9], 1);
    }
    __syncthreads();
    if (sK[t]) atomicAdd(&cntK[t], sK[t]);
    if (sU[t]) atomicAdd(&cntU[t], sU[t]);
    if (sI[t]) atomicAdd(&cntI[t], sI[t]);
}

// ---- tiny scans: bucket counts -> bucket offsets + gcur init ----
__global__ __launch_bounds__(256) void k_bucket_scan(const int* __restrict__ cntK,
        const int* __restrict__ cntU, const int* __restrict__ cntI,
        int* __restrict__ kg_boff, int* __restrict__ ui_boff, int* __restrict__ iu_boff,
        int* __restrict__ kg_g, int* __restrict__ ui_g, int* __restrict__ iu_g) {
    __shared__ int sc[256];
    int t = threadIdx.x;
#define SCAN1(cnt, boff, gcur) { \
    int v = cnt[t]; sc[t] = v; __syncthreads(); \
    for (int o = 1; o < 256; o <<= 1) { \
        int u = (t >= o) ? sc[t - o] : 0; __syncthreads(); sc[t] += u; __syncthreads(); } \
    int e = sc[t] - v; boff[t] = e; gcur[t] = e; \
    __syncthreads(); }
    SCAN1(cntK, kg_boff, kg_g)
    SCAN1(cntU, ui_boff, ui_g)
    SCAN1(cntI, iu_boff, iu_g)
#undef SCAN1
}

// ---- merged pass B: blocks [0,184) kg, [184,429) ui, [429,674) iu ----
struct SmB {
    union {
        struct { unsigned stage[KG_CHUNK]; int dest[KG_CHUNK]; } kg;
        struct { int2 stage[B8_CHUNK]; int dest[B8_CHUNK]; } b8;
    } u;
};

__device__ __forceinline__ void binB8_body(const int* __restrict__ key,
        const int* __restrict__ aux, const float* __restrict__ wv, int nE,
        int shift, int auxShift, int* __restrict__ gcur, int2* __restrict__ tmp,
        int cb, int2* stage, int* dest,
        int* cnt, int* boff, int* gbase, int* curl, int* sc) {
    int t = threadIdx.x;
    int base = cb * B8_CHUNK;
    int nloc = nE - base; if (nloc > B8_CHUNK) nloc = B8_CHUNK;
    cnt[t] = 0;
    __syncthreads();
    for (int i = t; i < nloc; i += 256)
        atomicAdd(&cnt[key[base + i] >> shift], 1);
    __syncthreads();
    int v = cnt[t];
    sc[t] = v;
    __syncthreads();
    for (int o = 1; o < 256; o <<= 1) {
        int u = (t >= o) ? sc[t - o] : 0;
        __syncthreads();
        sc[t] += u;
        __syncthreads();
    }
    boff[t] = sc[t] - v;
    curl[t] = sc[t] - v;
    gbase[t] = atomicAdd(&gcur[t], v);
    __syncthreads();
    int lowmask = (1 << shift) - 1;
    for (int i = t; i < nloc; i += 256) {
        int e = base + i;
        int k = key[e];
        int b = k >> shift;
        int2 pay;
        pay.x = aux[e] | ((k & lowmask) << auxShift);
        pay.y = __float_as_int(wv[e]);
        int pos = atomicAdd(&curl[b], 1);
        stage[pos] = pay;
        dest[pos] = gbase[b] + (pos - boff[b]);
    }
    __syncthreads();
    for (int s = t; s < nloc; s += 256) tmp[dest[s]] = stage[s];
}

__global__ __launch_bounds__(256) void k_binB_all(const int* __restrict__ eh,
        const int* __restrict__ et, const int* __restrict__ ety,
        int* __restrict__ kg_g, unsigned* __restrict__ kg_tmp,
        const int* __restrict__ iu, const int* __restrict__ ii,
        const float* __restrict__ iwf,
        int* __restrict__ ui_g, int2* __restrict__ ui_tmp,
        int* __restrict__ iu_g, int2* __restrict__ iu_tmp) {
    __shared__ SmB sm;
    __shared__ int cnt[256], boff[256], gbase[256], curl[256], sc[256];
    int bid = blockIdx.x;
    int t = threadIdx.x;
    if (bid < NB_BKG) {
        int base = bid * KG_CHUNK;
        int nloc = EKG - base; if (nloc > KG_CHUNK) nloc = KG_CHUNK;
        for (int i = t; i < KG_NBUCK; i += 256) cnt[i] = 0;
        __syncthreads();
        for (int i = t; i < nloc; i += 256)
            atomicAdd(&cnt[eh[base + i] >> 9], 1);
        __syncthreads();
        int v = (t < KG_NBUCK) ? cnt[t] : 0;
        sc[t] = v;
        __syncthreads();
        for (int o = 1; o < 256; o <<= 1) {
            int u = (t >= o) ? sc[t - o] : 0;
            __syncthreads();
            sc[t] += u;
            __syncthreads();
        }
        if (t < KG_NBUCK) {
            boff[t] = sc[t] - v;
            curl[t] = sc[t] - v;
            gbase[t] = atomicAdd(&kg_g[t], v);
        }
        __syncthreads();
        for (int i = t; i < nloc; i += 256) {
            int e = base + i;
            int h = eh[e];
            int b = h >> 9;
            unsigned pay = (unsigned)et[e] | ((unsigned)(ety[e] - 1) << 17)
                         | ((unsigned)(h & 511) << 21);
            int pos = atomicAdd(&curl[b], 1);
            sm.u.kg.stage[pos] = pay;
            sm.u.kg.dest[pos] = gbase[b] + (pos - boff[b]);
        }
        __syncthreads();
        for (int s = t; s < nloc; s += 256) kg_tmp[sm.u.kg.dest[s]] = sm.u.kg.stage[s];
    } else if (bid < NB_BKG + NB_B8) {
        binB8_body(iu, ii, iwf, EIN, 8, 17, ui_g, ui_tmp, bid - NB_BKG,
                   sm.u.b8.stage, sm.u.b8.dest, cnt, boff, gbase, curl, sc);
    } else {
        binB8_body(ii, iu, iwf, EIN, 9, 16, iu_g, iu_tmp, bid - NB_BKG - NB_B8,
                   sm.u.b8.stage, sm.u.b8.dest, cnt, boff, gbase, curl, sc);
    }
}

// ---- merged pass C: blocks [0,196) kg, [196,392) ui, [392,588) iu ----
struct SmC {
    union {
        unsigned kgstage[KG_CAP];
        int2 c8stage[C8_CAP];
    } u;
};

__device__ __forceinline__ void binC8_body(const int2* __restrict__ tmp,
        const int* __restrict__ boffg, int2* __restrict__ dst, int* __restrict__ off,
        int nnodes, int shift, int auxShift, int lb, int nb,
        int2* stage, int* curl, int* sc) {
    int b = lb;
    int nbase = b << shift;
    int nlim = nnodes - nbase; if (nlim > (1 << shift)) nlim = 1 << shift;
    if (nlim <= 0) return;
    int t = threadIdx.x;
    int r0 = boffg[b];
    int r1 = boffg[b + 1];
    int cntb = r1 - r0;
    int lowmask = (1 << shift) - 1;
    curl[t] = 0; curl[t + 256] = 0;
    __syncthreads();
    for (int s = t; s < cntb; s += 256)
        atomicAdd(&curl[(tmp[r0 + s].x >> auxShift) & lowmask], 1);
    __syncthreads();
    int v0 = curl[2 * t], v1 = curl[2 * t + 1];
    int s2 = v0 + v1;
    sc[t] = s2;
    __syncthreads();
    for (int o = 1; o < 256; o <<= 1) {
        int u = (t >= o) ? sc[t - o] : 0;
        __syncthreads();
        sc[t] += u;
        __syncthreads();
    }
    int excl = sc[t] - s2;
    curl[2 * t] = excl;
    curl[2 * t + 1] = excl + v0;
    if (2 * t < nlim) off[nbase + 2 * t] = r0 + excl;
    if (2 * t + 1 < nlim) off[nbase + 2 * t + 1] = r0 + excl + v0;
    if (b == nb - 1 && t == 0) off[nbase + nlim] = r1;  // sentinel
    __syncthreads();
    if (cntb <= C8_CAP) {
        for (int s = t; s < cntb; s += 256) {
            int2 pay = tmp[r0 + s];
            int l = (pay.x >> auxShift) & lowmask;
            int pos = atomicAdd(&curl[l], 1);
            stage[pos] = pay;
        }
        __syncthreads();
        for (int s = t; s < cntb; s += 256) dst[r0 + s] = stage[s];
    } else {
        for (int s = t; s < cntb; s += 256) {
            int2 pay = tmp[r0 + s];
            int l = (pay.x >> auxShift) & lowmask;
            int pos = atomicAdd(&curl[l], 1);
            dst[r0 + pos] = pay;
        }
    }
}

__global__ __launch_bounds__(256) void k_binC_all(const unsigned* __restrict__ kg_tmp,
        const int* __restrict__ kg_boff, unsigned* __restrict__ kg_tr, int* __restrict__ kg_off,
        const int2* __restrict__ ui_tmp, const int* __restrict__ ui_boff,
        int2* __restrict__ ui_iw, int* __restrict__ ui_off,
        const int2* __restrict__ iu_tmp, const int* __restrict__ iu_boff,
        int2* __restrict__ iu_iw, int* __restrict__ iu_off) {
    __shared__ SmC sm;
    __shared__ int curl[512];
    __shared__ int sc[256];
    int bid = blockIdx.x;
    int t = threadIdx.x;
    if (bid < NB_CKG) {
        int b = bid;
        int nbase = b << 9;
        int nlim = NE - nbase; if (nlim > 512) nlim = 512;
        if (nlim <= 0) return;
        int r0 = kg_boff[b];
        int r1 = kg_boff[b + 1];
        int cntb = r1 - r0;
        curl[t] = 0; curl[t + 256] = 0;
        __syncthreads();
        for (int s = t; s < cntb; s += 256)
            atomicAdd(&curl[(kg_tmp[r0 + s] >> 21) & 511], 1);
        __syncthreads();
        int v0 = curl[2 * t], v1 = curl[2 * t + 1];
        int s2 = v0 + v1;
        sc[t] = s2;
        __syncthreads();
        for (int o = 1; o < 256; o <<= 1) {
            int u = (t >= o) ? sc[t - o] : 0;
            __syncthreads();
            sc[t] += u;
            __syncthreads();
        }
        int excl = sc[t] - s2;
        curl[2 * t] = excl;
        curl[2 * t + 1] = excl + v0;
        if (2 * t < nlim) kg_off[nbase + 2 * t] = r0 + excl;
        if (2 * t + 1 < nlim) kg_off[nbase + 2 * t + 1] = r0 + excl + v0;
        if (b == NB_CKG - 1 && t == 0) kg_off[nbase + nlim] = r1;   // sentinel off[NE]
        __syncthreads();
        if (cntb <= KG_CAP) {
            for (int s = t; s < cntb; s += 256) {
                unsigned pay = kg_tmp[r0 + s];
                int l = (pay >> 21) & 511;
                int pos = atomicAdd(&curl[l], 1);
                sm.u.kgstage[pos] = pay;
            }
            __syncthreads();
            for (int s = t; s < cntb; s += 256) kg_tr[r0 + s] = sm.u.kgstage[s];
        } else {
            for (int s = t; s < cntb; s += 256) {
                unsigned pay = kg_tmp[r0 + s];
                int l = (pay >> 21) & 511;
                int pos = atomicAdd(&curl[l], 1);
                kg_tr[r0 + pos] = pay;
            }
        }
    } else if (bid < NB_CKG + NB_CUI) {
        binC8_body(ui_tmp, ui_boff, ui_iw, ui_off, NU, 8, 17,
                   bid - NB_CKG, NB_CUI, sm.u.c8stage, curl, sc);
    } else {
        binC8_body(iu_tmp, iu_boff, iu_iw, iu_off, NE, 9, 16,
                   bid - NB_CKG - NB_CUI, NB_CIU, sm.u.c8stage, curl, sc);
    }
}

// ---- fused per-layer kernel: blocks [0,NEB) entity aggregation, [NEB,NEB+NUB) users.
// Inner loops bit-identical to R5 (passing). FINAL=true folds the k_final epilogue:
// writes out=(base+acc_total)/3 directly, skips fp16 table + acc write-backs.
template<bool FINAL>
__global__ __launch_bounds__(256) void k_layer(const __half* __restrict__ qmH,
        const __half* __restrict__ relH, const __half* __restrict__ entH,
        const __half* __restrict__ usrH,
        const int* __restrict__ kg_off, const unsigned* __restrict__ kg_tr,
        const int* __restrict__ iu_off, const int2* __restrict__ iu_iw,
        const int* __restrict__ ui_off, const int2* __restrict__ ui_iw,
        float* __restrict__ eacc, __half* __restrict__ entHout,
        float* __restrict__ uacc, __half* __restrict__ usrHout,
        const float* __restrict__ ent0, const float* __restrict__ usr0,
        float* __restrict__ out) {
    int w = __builtin_amdgcn_readfirstlane(threadIdx.x >> 6);
    int lane = threadIdx.x & 63;
    int sub = lane >> 3;          // edge slot 0..7
    int li  = lane & 7;           // dims 8li..8li+7
    const float SC = 0.17677669529663687f; // 1/sqrt(32)
    const float NEG = -1e30f;
    const float inv3 = 1.f / 3.f;
    const int4* qmI  = (const int4*)qmH;
    const int4* entI = (const int4*)entH;
    const int4* relI = (const int4*)relH;
    const int4* usrI = (const int4*)usrH;

    if (blockIdx.x < NEB) {
        // ================= entity path =================
        int node = blockIdx.x * 4 + w;
        U16 qh; qh.v = qmI[(long)node * 8 + li];
        int b0 = kg_off[node], b1 = kg_off[node + 1];
        int deg = b1 - b0;

        float ssum = 0.f;
        float acc[8] = {0.f, 0.f, 0.f, 0.f, 0.f, 0.f, 0.f, 0.f};
        if (deg > 0) {
            int s = b0;
            int i0 = s + sub;
            unsigned tr = kg_tr[i0 < b1 ? i0 : b1 - 1];
            for (; s < b1; s += 8) {
                int ni = s + 8 + sub;
                unsigned trn = kg_tr[ni < b1 ? ni : b1 - 1];  // prefetch next step's payload
                bool has = (s + sub) < b1;
                int tl = tr & 0x1FFFF, rr = (tr >> 17) & 15;
                U16 rl; rl.v = relI[rr * 8 + li];
                U16 qt; qt.v = qmI[(long)tl * 8 + li];
                U16 ev; ev.v = entI[(long)tl * 8 + li];
                float p = 0.f;
#pragma unroll
                for (int k = 0; k < 4; k++) {
                    __half2 kk = __hmul2(qt.h[k], rl.h[k]);
                    p = fdot2a(qh.h[k], kk, p);
                }
                p = dpp_red4(p);
                float e = __expf(has ? p * SC : NEG);
                ssum += e;
#pragma unroll
                for (int k = 0; k < 4; k++) {
                    __half2 v2 = __hmul2(ev.h[k], rl.h[k]);
                    float2 vf = __half22float2(v2);
                    acc[2 * k]     += vf.x * e;
                    acc[2 * k + 1] += vf.y * e;
                }
                tr = trn;
            }
#pragma unroll
            for (int o = 8; o <= 32; o <<= 1) {
                ssum += __shfl_xor(ssum, o, 64);
#pragma unroll
                for (int k = 0; k < 8; k++) acc[k] += __shfl_xor(acc[k], o, 64);
            }
            float inv = 1.f / ssum;
#pragma unroll
            for (int k = 0; k < 8; k++) acc[k] *= inv;
            float ss = 0.f;
#pragma unroll
            for (int k = 0; k < 8; k++) ss += acc[k] * acc[k];
            ss += __shfl_xor(ss, 1, 64);
            ss += __shfl_xor(ss, 2, 64);
            ss += __shfl_xor(ss, 4, 64);
            float nsc = 1.f / fmaxf(sqrtf(ss), 1e-12f);
#pragma unroll
            for (int k = 0; k < 8; k++) acc[k] *= nsc;
        }

        // user -> entity gather
        int c0 = iu_off[node], c1 = iu_off[node + 1];
        if (c1 > c0) {
            float ua[8] = {0.f, 0.f, 0.f, 0.f, 0.f, 0.f, 0.f, 0.f};
            int t2 = c0;
            int j0 = t2 + sub;
            int2 pw = iu_iw[j0 < c1 ? j0 : c1 - 1];
            for (; t2 < c1; t2 += 8) {
                int nj = t2 + 8 + sub;
                int2 pwn = iu_iw[nj < c1 ? nj : c1 - 1];
                bool has = (t2 + sub) < c1;
                float wv = has ? __int_as_float(pw.y) : 0.f;
                U16 uu; uu.v = usrI[(long)(pw.x & 0xFFFF) * 8 + li];
#pragma unroll
                for (int k = 0; k < 4; k++) {
                    float2 uf = __half22float2(uu.h[k]);
                    ua[2 * k]     += wv * uf.x;
                    ua[2 * k + 1] += wv * uf.y;
                }
                pw = pwn;
            }
#pragma unroll
            for (int o = 8; o <= 32; o <<= 1) {
#pragma unroll
                for (int k = 0; k < 8; k++) ua[k] += __shfl_xor(ua[k], o, 64);
            }
#pragma unroll
            for (int k = 0; k < 8; k++) acc[k] += ua[k];
        }

        if (sub == 0) {
            long base = (long)node * 16 + 2 * li;
            float4* eacc4 = (float4*)eacc;
            float4 e0 = eacc4[base], e1 = eacc4[base + 1];
            e0.x += acc[0]; e0.y += acc[1]; e0.z += acc[2]; e0.w += acc[3];
            e1.x += acc[4]; e1.y += acc[5]; e1.z += acc[6]; e1.w += acc[7];
            if (!FINAL) {
                eacc4[base] = e0; eacc4[base + 1] = e1;
                U16 ho;
                ho.h[0] = __floats2half2_rn(acc[0], acc[1]);
                ho.h[1] = __floats2half2_rn(acc[2], acc[3]);
                ho.h[2] = __floats2half2_rn(acc[4], acc[5]);
                ho.h[3] = __floats2half2_rn(acc[6], acc[7]);
                ((int4*)entHout)[(long)node * 8 + li] = ho.v;
            } else {
                const float4* a4 = (const float4*)ent0;
                float4 a0 = a4[base], a1 = a4[base + 1];
                float4 o0, o1;
                o0.x = (a0.x + e0.x) * inv3; o0.y = (a0.y + e0.y) * inv3;
                o0.z = (a0.z + e0.z) * inv3; o0.w = (a0.w + e0.w) * inv3;
                o1.x = (a1.x + e1.x) * inv3; o1.y = (a1.y + e1.y) * inv3;
                o1.z = (a1.z + e1.z) * inv3; o1.w = (a1.w + e1.w) * inv3;
                float4* oute = (float4*)out + (long)NU * 16;
                oute[base] = o0; oute[base + 1] = o1;
            }
        }
    } else {
        // ================= user path =================
        int node = (blockIdx.x - NEB) * 4 + w;
        int b0 = ui_off[node], b1 = ui_off[node + 1];
        float ax[8] = {0.f, 0.f, 0.f, 0.f, 0.f, 0.f, 0.f, 0.f};
        if (b1 > b0) {
            int s = b0;
            int j0 = s + sub;
            int2 pw = ui_iw[j0 < b1 ? j0 : b1 - 1];
            for (; s < b1; s += 8) {
                int nj = s + 8 + sub;
                int2 pwn = ui_iw[nj < b1 ? nj : b1 - 1];
                bool has = (s + sub) < b1;
                float wv = has ? __int_as_float(pw.y) : 0.f;
                U16 uu; uu.v = entI[(long)(pw.x & 0x1FFFF) * 8 + li];
#pragma unroll
                for (int k = 0; k < 4; k++) {
                    float2 uf = __half22float2(uu.h[k]);
                    ax[2 * k]     += wv * uf.x;
                    ax[2 * k + 1] += wv * uf.y;
                }
                pw = pwn;
            }
#pragma unroll
            for (int o = 8; o <= 32; o <<= 1) {
#pragma unroll
                for (int k = 0; k < 8; k++) ax[k] += __shfl_xor(ax[k], o, 64);
            }
        }
        if (sub == 0) {
            long base = (long)node * 16 + 2 * li;
            float4* uacc4 = (float4*)uacc;
            float4 u0 = uacc4[base], u1 = uacc4[base + 1];
            u0.x += ax[0]; u0.y += ax[1]; u0.z += ax[2]; u0.w += ax[3];
            u1.x += ax[4]; u1.y += ax[5]; u1.z += ax[6]; u1.w += ax[7];
            if (!FINAL) {
                uacc4[base] = u0; uacc4[base + 1] = u1;
                U16 ho;
                ho.h[0] = __floats2half2_rn(ax[0], ax[1]);
                ho.h[1] = __floats2half2_rn(ax[2], ax[3]);
                ho.h[2] = __floats2half2_rn(ax[4], ax[5]);
                ho.h[3] = __floats2half2_rn(ax[6], ax[7]);
                ((int4*)usrHout)[(long)node * 8 + li] = ho.v;
            } else {
                const float4* a4 = (const float4*)usr0;
                float4 a0 = a4[base], a1 = a4[base + 1];
                float4 o0, o1;
                o0.x = (a0.x + u0.x) * inv3; o0.y = (a0.y + u0.y) * inv3;
                o0.z = (a0.z + u0.z) * inv3; o0.w = (a0.w + u0.w) * inv3;
                o1.x = (a1.x + u1.x) * inv3; o1.y = (a1.y + u1.y) * inv3;
                o1.z = (a1.z + u1.z) * inv3; o1.w = (a1.w + u1.w) * inv3;
                float4* outu = (float4*)out;
                outu[base] = o0; outu[base + 1] = o1;
            }
        }
    }
}

extern "C" void kernel_launch(void* const* d_in, const int* in_sizes, int n_in,
                              void* d_out, int out_size, void* d_ws, size_t ws_size,
                              hipStream_t stream) {
    const float* usr0  = (const float*)d_in[1];
    const float* ent0  = (const float*)d_in[2];
    const int*   inter = (const int*)d_in[3];
    const float* iwf   = (const float*)d_in[4];
    const int*   eidx  = (const int*)d_in[5];
    const int*   etype = (const int*)d_in[6];
    const float* relf  = (const float*)d_in[7];
    const float* wqf   = (const float*)d_in[8];
    float* out = (float*)d_out;

    const int* eh = eidx;
    const int* et = eidx + EKG;
    const int* iu = inter;
    const int* ii = inter + EIN;

    // ---- workspace layout (4B words) ----
    float* p = (float*)d_ws;
    float* eacc = p;  p += (long)NE * DIM;        // contiguous accs -> one memset
    float* uacc = p;  p += (long)NU * DIM;
    __half* qmH   = (__half*)p;  p += (long)NE * DIM / 2;
    __half* entHa = (__half*)p;  p += (long)NE * DIM / 2;
    __half* entHb = (__half*)p;  p += (long)NE * DIM / 2;
    __half* usrHa = (__half*)p;  p += (long)NU * DIM / 2;
    __half* usrHb = (__half*)p;  p += (long)NU * DIM / 2;
    __half* relH  = (__half*)p;  p += (long)NRELS * DIM / 2;
    int* cntK = (int*)p;        p += 256;         // bucket counts (contiguous -> one memset)
    int* cntU = (int*)p;        p += 256;
    int* cntI = (int*)p;        p += 256;
    int* kg_boff = (int*)p;     p += 256;         // bucket offsets (pristine)
    int* ui_boff = (int*)p;     p += 256;
    int* iu_boff = (int*)p;     p += 256;
    int* kg_off = (int*)p;      p += NE + 2;      // per-node CSR offsets (written by pass C)
    int* ui_off = (int*)p;      p += NU + 2;
    int* iu_off = (int*)p;      p += NE + 2;
    int* kg_g   = (int*)p;      p += 256;         // pass-B reservation cursors
    int* ui_g   = (int*)p;      p += 256;
    int* iu_g   = (int*)p;      p += 256;
    unsigned* kg_tr  = (unsigned*)p; p += EKG;
    unsigned* kg_tmp = (unsigned*)p; p += EKG;
    int2* ui_iw  = (int2*)p;    p += (long)EIN * 2;
    int2* ui_tmp = (int2*)p;    p += (long)EIN * 2;
    int2* iu_iw  = (int2*)p;    p += (long)EIN * 2;
    int2* iu_tmp = (int2*)p;    p += (long)EIN * 2;

    const int B = 256;

    // ---- init: zero accumulators + bucket counters; fp16 mirrors ----
    hipMemsetAsync(eacc, 0, (size_t)(NE + NU) * DIM * 4, stream);
    hipMemsetAsync(cntK, 0, (size_t)768 * 4, stream);
    k_castH<<<NE * 16 / B, B, 0, stream>>>((const float4*)ent0, (const float4*)usr0,
                                           (const float4*)relf,
                                           (int2*)entHa, (int2*)usrHa, (int2*)relH);

    // ---- CSR build ----
    k_hist_bucket<<<512, 256, 0, stream>>>(eh, iu, ii, cntK, cntU, cntI);
    k_bucket_scan<<<1, 256, 0, stream>>>(cntK, cntU, cntI, kg_boff, ui_boff, iu_boff,
                                         kg_g, ui_g, iu_g);
    k_binB_all<<<NB_BKG + NB_B8 + NB_B8, 256, 0, stream>>>(eh, et, etype, kg_g, kg_tmp,
                                                           iu, ii, iwf,
                                                           ui_g, ui_tmp, iu_g, iu_tmp);
    k_binC_all<<<NB_CKG + NB_CUI + NB_CIU, 256, 0, stream>>>(kg_tmp, kg_boff, kg_tr, kg_off,
                                                             ui_tmp, ui_boff, ui_iw, ui_off,
                                                             iu_tmp, iu_boff, iu_iw, iu_off);

    // ---- layer 0 ----
    k_gemm_f<<<NE / 16, 256, 0, stream>>>(ent0, wqf, qmH);
    k_layer<false><<<NEB + NUB, 256, 0, stream>>>(qmH, relH, entHa, usrHa,
                                                  kg_off, kg_tr, iu_off, iu_iw, ui_off, ui_iw,
                                                  eacc, entHb, uacc, usrHb,
                                                  nullptr, nullptr, nullptr);
    // ---- layer 1 (folds k_final) ----
    k_gemm_h<<<NE / 16, 256, 0, stream>>>(entHb, wqf, qmH);
    k_layer<true><<<NEB + NUB, 256, 0, stream>>>(qmH, relH, entHb, usrHb,
                                                 kg_off, kg_tr, iu_off, iu_iw, ui_off, ui_iw,
                                                 eacc, entHa, uacc, usrHa,
                                                 ent0, usr0, out);
}